// Round 1
// baseline (5426.591 us; speedup 1.0000x reference)
//
#include <hip/hip_runtime.h>
#include <math.h>

// ---------------- problem constants ----------------
constexpr int B = 16, S = 384, H = 768;
constexpr int BS = B * S;                           // 6144
constexpr long long PAIRS = (long long)S * (S + 1) / 2;  // 73920
constexpr float INV = 0.125f;                       // 1/sqrt(64)

// ---------------- rope table (f64 on device, cast to f32) ----------------
__global__ void rope_table_kernel(float* tab) {
  int s = blockIdx.x, i = threadIdx.x;              // 384 x 32
  double ang = (double)s / pow(10000.0, (double)i / 32.0);
  tab[s * 64 + 2 * i]     = (float)cos(ang);
  tab[s * 64 + 2 * i + 1] = (float)sin(ang);
}

// ---------------- rope + mask, in place on [BS, nh*64] ----------------
__global__ __launch_bounds__(256) void rope_mask_kernel(
    float* __restrict__ buf, const float* __restrict__ mask,
    const float* __restrict__ tab, int nh) {
  int idx = blockIdx.x * blockDim.x + threadIdx.x;
  int total = BS * nh * 32;
  if (idx >= total) return;
  int i  = idx & 31;
  int h  = (idx >> 5) % nh;
  int bs = idx / (32 * nh);
  int s  = bs % S;
  float c  = tab[s * 64 + 2 * i];
  float sn = tab[s * 64 + 2 * i + 1];
  float m = mask[bs];
  float* p = buf + (size_t)bs * (nh * 64) + h * 64 + 2 * i;
  float x0 = p[0], x1 = p[1];
  p[0] = m * (x0 * c - x1 * sn);
  p[1] = m * (x1 * c + x0 * sn);
}

// ---------------- general NT GEMM: C = act(alpha*A@W^T + bias) ----------------
// A: [M,K] lda, W: [N,K] ldw, C: [M,N] ldc.  Batched via blockIdx.z with
// (zb, zh) = (z/nh, z%nh) strides so the same kernel does per-(b,h) scores.
// BM=128, BN=64, BK=16, 256 threads, 8x4 per thread. M%128==0 assumed.
template <int ACT>
__global__ __launch_bounds__(256) void gemm_nt_kernel(
    const float* __restrict__ A, const float* __restrict__ W,
    const float* __restrict__ bias, float* __restrict__ C,
    int M, int N, int K, int lda, int ldw, int ldc, float alpha, int nh,
    long long sAb, long long sAh, long long sWb, long long sWh,
    long long sCb, long long sCh) {
  int z = blockIdx.z;
  int zb = z / nh, zh = z - zb * nh;
  A += zb * sAb + zh * sAh;
  W += zb * sWb + zh * sWh;
  C += zb * sCb + zh * sCh;

  __shared__ float As[16][132];   // [k][m], padded: row stride 132*4B (16B aligned)
  __shared__ float Ws[16][68];    // [k][n]

  const int tid = threadIdx.x;
  const int tx = tid & 15, ty = tid >> 4;
  const int m0 = blockIdx.y * 128, n0 = blockIdx.x * 64;

  float acc[8][4];
#pragma unroll
  for (int i = 0; i < 8; ++i)
#pragma unroll
    for (int j = 0; j < 4; ++j) acc[i][j] = 0.f;

  const int ar = (tid * 4) >> 4;   // 0..63
  const int ak = (tid * 4) & 15;   // 0,4,8,12

  for (int k0 = 0; k0 < K; k0 += 16) {
#pragma unroll
    for (int it = 0; it < 2; ++it) {   // A tile: 128 rows x 16 k
      int r = ar + it * 64;
      const float4 v = *reinterpret_cast<const float4*>(
          &A[(size_t)(m0 + r) * lda + k0 + ak]);
      As[ak + 0][r] = v.x; As[ak + 1][r] = v.y;
      As[ak + 2][r] = v.z; As[ak + 3][r] = v.w;
    }
    {                                   // W tile: 64 n x 16 k (guard N edge)
      int n = n0 + ar;
      float4 v = make_float4(0.f, 0.f, 0.f, 0.f);
      if (n < N) v = *reinterpret_cast<const float4*>(
          &W[(size_t)n * ldw + k0 + ak]);
      Ws[ak + 0][ar] = v.x; Ws[ak + 1][ar] = v.y;
      Ws[ak + 2][ar] = v.z; Ws[ak + 3][ar] = v.w;
    }
    __syncthreads();
#pragma unroll
    for (int kk = 0; kk < 16; ++kk) {
      const float4 a0 = *reinterpret_cast<const float4*>(&As[kk][ty * 8]);
      const float4 a1 = *reinterpret_cast<const float4*>(&As[kk][ty * 8 + 4]);
      const float4 b0 = *reinterpret_cast<const float4*>(&Ws[kk][tx * 4]);
      const float av[8] = {a0.x, a0.y, a0.z, a0.w, a1.x, a1.y, a1.z, a1.w};
      const float bv[4] = {b0.x, b0.y, b0.z, b0.w};
#pragma unroll
      for (int i = 0; i < 8; ++i)
#pragma unroll
        for (int j = 0; j < 4; ++j) acc[i][j] = fmaf(av[i], bv[j], acc[i][j]);
    }
    __syncthreads();
  }

#pragma unroll
  for (int i = 0; i < 8; ++i) {
    const int m = m0 + ty * 8 + i;
#pragma unroll
    for (int j = 0; j < 4; ++j) {
      const int n = n0 + tx * 4 + j;
      if (n < N) {
        float v = alpha * acc[i][j];
        if (bias) v += bias[n];
        if (ACT == 1) v = fmaxf(v, 0.f);
        C[(size_t)m * ldc + n] = v;
      }
    }
  }
}

// ---------------- NN GEMM with relu + accumulate: C (+)= relu(A@B) ----------------
// A: [M,K] lda (adj), B: [K,N] ldb (hr), C: [M,N] ldc (acc). Batched over z.
// BM=BN=64, BK=16, 256 threads, 4x4. All dims multiples of tile here.
__global__ __launch_bounds__(256) void gemm_nn_acc_kernel(
    const float* __restrict__ A, const float* __restrict__ Bm,
    float* __restrict__ C, int M, int N, int K, int lda, int ldb, int ldc,
    long long sA, long long sB, long long sC, int init) {
  int z = blockIdx.z;
  A += z * sA; Bm += z * sB; C += z * sC;

  __shared__ float As[16][68];   // [k][m]
  __shared__ float Bs[16][68];   // [k][n]

  const int tid = threadIdx.x;
  const int tx = tid & 15, ty = tid >> 4;
  const int m0 = blockIdx.y * 64, n0 = blockIdx.x * 64;

  float acc[4][4];
#pragma unroll
  for (int i = 0; i < 4; ++i)
#pragma unroll
    for (int j = 0; j < 4; ++j) acc[i][j] = 0.f;

  for (int k0 = 0; k0 < K; k0 += 16) {
    {   // A tile 64 m x 16 k, transpose-store
      int idx = tid * 4, r = idx >> 4, kk = idx & 15;
      const float4 v = *reinterpret_cast<const float4*>(
          &A[(size_t)(m0 + r) * lda + k0 + kk]);
      As[kk + 0][r] = v.x; As[kk + 1][r] = v.y;
      As[kk + 2][r] = v.z; As[kk + 3][r] = v.w;
    }
    {   // B tile 16 k x 64 n, direct store
      int idx = tid * 4, kk = idx >> 6, n = idx & 63;
      const float4 v = *reinterpret_cast<const float4*>(
          &Bm[(size_t)(k0 + kk) * ldb + n0 + n]);
      *reinterpret_cast<float4*>(&Bs[kk][n]) = v;
    }
    __syncthreads();
#pragma unroll
    for (int kk = 0; kk < 16; ++kk) {
      const float4 a = *reinterpret_cast<const float4*>(&As[kk][ty * 4]);
      const float4 b = *reinterpret_cast<const float4*>(&Bs[kk][tx * 4]);
      const float av[4] = {a.x, a.y, a.z, a.w};
      const float bv[4] = {b.x, b.y, b.z, b.w};
#pragma unroll
      for (int i = 0; i < 4; ++i)
#pragma unroll
        for (int j = 0; j < 4; ++j) acc[i][j] = fmaf(av[i], bv[j], acc[i][j]);
    }
    __syncthreads();
  }

#pragma unroll
  for (int i = 0; i < 4; ++i) {
#pragma unroll
    for (int j = 0; j < 4; ++j) {
      size_t off = (size_t)(m0 + ty * 4 + i) * ldc + n0 + tx * 4 + j;
      float v = fmaxf(acc[i][j], 0.f);
      C[off] = init ? v : (C[off] + v);
    }
  }
}

// ---------------- symmetrize: M[i][j] = M[j][i] for i>j (per matrix) ----------------
// Writes only the lower triangle from upper-triangle reads -> race-free.
__global__ __launch_bounds__(384) void symmetrize_kernel(float* __restrict__ Mt) {
  int bhi = blockIdx.x;                // (mat)*S + i, mat in [0, B*9)
  int mat = bhi / S, i = bhi % S;
  int j = threadIdx.x;                 // 0..383
  float* base = Mt + (size_t)mat * S * S;
  if (j < i) base[(size_t)i * S + j] = base[(size_t)j * S + i];
}

// ---------------- softmax over row, then *(att != 0), in place ----------------
__global__ __launch_bounds__(128) void softmax_mask_kernel(float* __restrict__ Mt) {
  __shared__ float red[128];
  int row = blockIdx.x;                // B*9*S rows
  float* r = Mt + (size_t)row * S;
  int t = threadIdx.x;
  float v[3];
  float mx = -INFINITY;
#pragma unroll
  for (int q = 0; q < 3; ++q) { v[q] = r[t + q * 128]; mx = fmaxf(mx, v[q]); }
  red[t] = mx; __syncthreads();
  for (int off = 64; off > 0; off >>= 1) {
    if (t < off) red[t] = fmaxf(red[t], red[t + off]);
    __syncthreads();
  }
  mx = red[0]; __syncthreads();
  float e[3], s = 0.f;
#pragma unroll
  for (int q = 0; q < 3; ++q) { e[q] = expf(v[q] - mx); s += e[q]; }
  red[t] = s; __syncthreads();
  for (int off = 64; off > 0; off >>= 1) {
    if (t < off) red[t] += red[t + off];
    __syncthreads();
  }
  float invs = 1.f / red[0];
#pragma unroll
  for (int q = 0; q < 3; ++q)
    r[t + q * 128] = (v[q] != 0.f) ? e[q] * invs : 0.f;
}

// ---------------- RGAT finalize: feat = LN(relu(acc)/9) ----------------
__global__ __launch_bounds__(256) void ln_finalize_kernel(
    const float* __restrict__ acc, float* __restrict__ feat) {
  __shared__ float red[256];
  int row = blockIdx.x;                // B*S
  const float* a = acc + (size_t)row * H;
  float* f = feat + (size_t)row * H;
  int t = threadIdx.x;
  float v[3];
  float s = 0.f;
#pragma unroll
  for (int q = 0; q < 3; ++q) { v[q] = fmaxf(a[t + q * 256], 0.f) / 9.0f; s += v[q]; }
  red[t] = s; __syncthreads();
  for (int off = 128; off > 0; off >>= 1) {
    if (t < off) red[t] += red[t + off];
    __syncthreads();
  }
  float mean = red[0] / (float)H; __syncthreads();
  float s2 = 0.f;
#pragma unroll
  for (int q = 0; q < 3; ++q) { float d = v[q] - mean; s2 += d * d; }
  red[t] = s2; __syncthreads();
  for (int off = 128; off > 0; off >>= 1) {
    if (t < off) red[t] += red[t + off];
    __syncthreads();
  }
  float var = red[0] / (float)H;
  float rs = rsqrtf(var + 1e-5f);
#pragma unroll
  for (int q = 0; q < 3; ++q) f[t + q * 256] = (v[q] - mean) * rs;
}

// ---------------- concat [x, feat] -> inp [BS, 1536] (float4) ----------------
__global__ __launch_bounds__(256) void concat_kernel(
    const float* __restrict__ x, const float* __restrict__ feat,
    float* __restrict__ inp) {
  int idx = blockIdx.x * blockDim.x + threadIdx.x;   // over BS*192 float4s
  if (idx >= BS * (H / 4)) return;
  int bs = idx / (H / 4), c4 = idx % (H / 4);
  const float4* x4 = reinterpret_cast<const float4*>(x);
  const float4* f4 = reinterpret_cast<const float4*>(feat);
  float4* o4 = reinterpret_cast<float4*>(inp);
  o4[(size_t)bs * (2 * H / 4) + c4] = x4[idx];
  o4[(size_t)bs * (2 * H / 4) + (H / 4) + c4] = f4[idx];
}

// ---------------- triu gather: out[b, p, cbase+h] = (relu?) src[b,h,i,j] ----------------
__global__ __launch_bounds__(384) void gather_kernel(
    const float* __restrict__ src, float* __restrict__ out,
    int nh_src, int hc, int cbase, int do_relu) {
  int bi = blockIdx.x;                 // b*S + i
  int b = bi / S, i = bi % S;
  int j = threadIdx.x;                 // 0..383
  if (j < i) return;
  long long p = (long long)i * S - (long long)i * (i - 1) / 2 + (j - i);
  float* o = out + ((size_t)b * PAIRS + p) * 16 + cbase;
  for (int h = 0; h < hc; ++h) {
    float v = src[(((size_t)b * nh_src + h) * S + i) * S + j];
    if (do_relu) v = fmaxf(v, 0.f);
    o[h] = v;
  }
}

// ---------------- launch ----------------
extern "C" void kernel_launch(void* const* d_in, const int* in_sizes, int n_in,
                              void* d_out, int out_size, void* d_ws, size_t ws_size,
                              hipStream_t stream) {
  (void)in_sizes; (void)n_in; (void)out_size; (void)ws_size;
  const float* x          = (const float*)d_in[0];
  const float* mask       = (const float*)d_in[1];
  const float* wq4gt_w    = (const float*)d_in[2];
  const float* wq4gt_b    = (const float*)d_in[3];
  const float* wk4gt_w    = (const float*)d_in[4];
  const float* wk4gt_b    = (const float*)d_in[5];
  const float* wq4g_rep_w = (const float*)d_in[6];
  const float* wq4g_rep_b = (const float*)d_in[7];
  const float* wq4g_sc_w  = (const float*)d_in[8];
  const float* wq4g_sc_b  = (const float*)d_in[9];
  const float* wk4g_rep_w = (const float*)d_in[10];
  const float* wk4g_rep_b = (const float*)d_in[11];
  const float* wk4g_sc_w  = (const float*)d_in[12];
  const float* wk4g_sc_b  = (const float*)d_in[13];
  const float* rgat_w     = (const float*)d_in[14];
  const float* wq4t_w     = (const float*)d_in[15];
  const float* wq4t_b     = (const float*)d_in[16];
  const float* wk4t_w     = (const float*)d_in[17];
  const float* wk4t_b     = (const float*)d_in[18];
  const float* wq_rep_w   = (const float*)d_in[19];
  const float* wq_rep_b   = (const float*)d_in[20];
  const float* wq_sc_w    = (const float*)d_in[21];
  const float* wq_sc_b    = (const float*)d_in[22];
  const float* wk_rep_w   = (const float*)d_in[23];
  const float* wk_rep_b   = (const float*)d_in[24];
  const float* wk_sc_w    = (const float*)d_in[25];
  const float* wk_sc_b    = (const float*)d_in[26];
  float* out = (float*)d_out;
  float* ws  = (float*)d_ws;

  // workspace layout (floats); total ~233 MB
  float* t_rope = ws;                                  // 24576
  float* t_sct  = t_rope + 24576;                      // B*S*S      (9.4 MB)
  float* t_tsq  = t_sct  + (size_t)B * S * S;          // BS*64
  float* t_tsk  = t_tsq  + (size_t)BS * 64;            // BS*64
  float* t_rep  = t_tsk  + (size_t)BS * 64;            // BS*960     (reused)
  float* t_q    = t_rep  + (size_t)BS * 960;           // BS*576     (later qp BS*384)
  float* t_k    = t_q    + (size_t)BS * 576;           // BS*576     (later kp)
  float* t_scg  = t_k    + (size_t)BS * 576;           // B*9*S*S    (85 MB; later score_p B*6*S*S)
  float* t_feat = t_scg  + (size_t)B * 9 * S * S;      // BS*H
  float* t_acc  = t_feat + (size_t)BS * H;             // BS*H
  float* t_hr   = t_acc  + (size_t)BS * H;             // BS*H
  float* t_inp  = t_hr   + (size_t)BS * H;             // BS*2H

  // plain (non-batched) NT gemm helper
  auto gemm0 = [&](const float* A, const float* W, const float* bias, float* C,
                   int M, int N, int K) {
    gemm_nt_kernel<0><<<dim3((N + 63) / 64, M / 128, 1), 256, 0, stream>>>(
        A, W, bias, C, M, N, K, K, K, N, 1.0f, 1, 0, 0, 0, 0, 0, 0);
  };
  auto gemm1 = [&](const float* A, const float* W, const float* bias, float* C,
                   int M, int N, int K) {
    gemm_nt_kernel<1><<<dim3((N + 63) / 64, M / 128, 1), 256, 0, stream>>>(
        A, W, bias, C, M, N, K, K, K, N, 1.0f, 1, 0, 0, 0, 0, 0, 0);
  };
  // batched per-(b,h) score: C[b,h] = INV * Q[b,h] @ K[b,h]^T from [B,S,nh*64] layout
  auto score_bmm = [&](const float* Q, const float* Kp, float* Cb, int nh) {
    gemm_nt_kernel<0><<<dim3(S / 64, S / 128, B * nh), 256, 0, stream>>>(
        Q, Kp, nullptr, Cb, S, S, 64, nh * 64, nh * 64, S, INV, nh,
        (long long)S * nh * 64, 64, (long long)S * nh * 64, 64,
        (long long)nh * S * S, (long long)S * S);
  };
  auto rope = [&](float* buf, int nh) {
    int total = BS * nh * 32;
    rope_mask_kernel<<<(total + 255) / 256, 256, 0, stream>>>(buf, mask, t_rope, nh);
  };

  rope_table_kernel<<<S, 32, 0, stream>>>(t_rope);

  // ----- graph layer: token-pair head (thr_g, channel 15) -----
  gemm0(x, wq4gt_w, wq4gt_b, t_tsq, BS, 64, H);
  gemm0(x, wk4gt_w, wk4gt_b, t_tsk, BS, 64, H);
  rope(t_tsq, 1);
  rope(t_tsk, 1);
  score_bmm(t_tsq, t_tsk, t_sct, 1);
  gather_kernel<<<BS, 384, 0, stream>>>(t_sct, out, 1, 1, 15, 1);

  // ----- graph layer: 9-head score (sc_g channels 7..14) + adj -----
  gemm1(x, wq4g_rep_w, wq4g_rep_b, t_rep, BS, 672, H);
  gemm0(t_rep, wq4g_sc_w, wq4g_sc_b, t_q, BS, 576, 672);
  rope(t_q, 9);
  gemm1(x, wk4g_rep_w, wk4g_rep_b, t_rep, BS, 672, H);
  gemm0(t_rep, wk4g_sc_w, wk4g_sc_b, t_k, BS, 576, 672);
  rope(t_k, 9);
  score_bmm(t_q, t_k, t_scg, 9);
  gather_kernel<<<BS, 384, 0, stream>>>(t_scg, out, 9, 8, 7, 0);

  // att = symmetrized score (in place), adj = softmax(att)*(att!=0) (in place)
  symmetrize_kernel<<<B * 9 * S, 384, 0, stream>>>(t_scg);
  softmax_mask_kernel<<<B * 9 * S, 128, 0, stream>>>(t_scg);

  // ----- RGAT x2 -----
  const float* fsrc = x;
  for (int l = 0; l < 2; ++l) {
    for (int r = 0; r < 9; ++r) {
      gemm0(fsrc, rgat_w + (size_t)(l * 9 + r) * H * H, nullptr, t_hr, BS, H, H);
      gemm_nn_acc_kernel<<<dim3(H / 64, S / 64, B), 256, 0, stream>>>(
          t_scg + (size_t)r * S * S, t_hr, t_acc, S, H, S, S, H, H,
          (long long)9 * S * S, (long long)S * H, (long long)S * H, (r == 0) ? 1 : 0);
    }
    ln_finalize_kernel<<<BS, 256, 0, stream>>>(t_acc, t_feat);
    fsrc = t_feat;
  }

  // ----- prediction head -----
  concat_kernel<<<(BS * (H / 4) + 255) / 256, 256, 0, stream>>>(x, t_feat, t_inp);

  gemm0(t_inp, wq4t_w, wq4t_b, t_tsq, BS, 64, 2 * H);
  gemm0(t_inp, wk4t_w, wk4t_b, t_tsk, BS, 64, 2 * H);
  rope(t_tsq, 1);
  rope(t_tsk, 1);
  score_bmm(t_tsq, t_tsk, t_sct, 1);
  gather_kernel<<<BS, 384, 0, stream>>>(t_sct, out, 1, 1, 6, 1);   // thr_p ch 6

  gemm1(t_inp, wq_rep_w, wq_rep_b, t_rep, BS, 960, 2 * H);
  gemm0(t_rep, wq_sc_w, wq_sc_b, t_q, BS, 384, 960);
  rope(t_q, 6);
  gemm1(t_inp, wk_rep_w, wk_rep_b, t_rep, BS, 960, 2 * H);
  gemm0(t_rep, wk_sc_w, wk_sc_b, t_k, BS, 384, 960);
  rope(t_k, 6);
  score_bmm(t_q, t_k, t_scg, 6);                                   // reuse adj buffer
  gather_kernel<<<BS, 384, 0, stream>>>(t_scg, out, 6, 6, 0, 0);   // sc_p ch 0..5
}

// Round 2
// 1252.265 us; speedup vs baseline: 4.3334x; 4.3334x over previous
//
#include <hip/hip_runtime.h>
#include <math.h>

typedef unsigned short ushort_t;
typedef __attribute__((ext_vector_type(8))) short short8;
typedef __attribute__((ext_vector_type(4))) float f32x4;

// ---------------- problem constants ----------------
constexpr int B = 16, S = 384, H = 768;
constexpr int BS = B * S;                                // 6144
constexpr long long PAIRS = (long long)S * (S + 1) / 2;  // 73920
constexpr float INV = 0.125f;                            // 1/sqrt(64)

__device__ __forceinline__ ushort_t f2bf(float f) {
  unsigned int u = __float_as_uint(f);
  u += 0x7FFF + ((u >> 16) & 1);       // round-to-nearest-even
  return (ushort_t)(u >> 16);
}

__device__ __forceinline__ void glds16(const ushort_t* g, ushort_t* l) {
  __builtin_amdgcn_global_load_lds(
      (const __attribute__((address_space(1))) unsigned int*)g,
      (__attribute__((address_space(3))) unsigned int*)l, 16, 0, 0);
}

// ---------------- rope table ----------------
__global__ void rope_table_kernel(float* tab) {
  int s = blockIdx.x, i = threadIdx.x;  // 384 x 32
  double ang = (double)s / pow(10000.0, (double)i / 32.0);
  tab[s * 64 + 2 * i]     = (float)cos(ang);
  tab[s * 64 + 2 * i + 1] = (float)sin(ang);
}

// ---------------- rope + mask: fp32 src -> bf16 dst ----------------
__global__ __launch_bounds__(256) void rope_cvt_kernel(
    const float* __restrict__ src, ushort_t* __restrict__ dst,
    const float* __restrict__ mask, const float* __restrict__ tab, int nh) {
  int idx = blockIdx.x * blockDim.x + threadIdx.x;
  int total = BS * nh * 32;
  if (idx >= total) return;
  int i  = idx & 31;
  int h  = (idx >> 5) % nh;
  int bs = idx / (32 * nh);
  int s  = bs % S;
  float c  = tab[s * 64 + 2 * i];
  float sn = tab[s * 64 + 2 * i + 1];
  float m  = mask[bs];
  size_t o = (size_t)bs * (nh * 64) + h * 64 + 2 * i;
  float x0 = src[o], x1 = src[o + 1];
  dst[o]     = f2bf(m * (x0 * c - x1 * sn));
  dst[o + 1] = f2bf(m * (x1 * c + x0 * sn));
}

// ---------------- bulk fp32 -> bf16 convert with row padding ----------------
constexpr int NJOBS = 14;
struct CvtJobs {
  const float* src[NJOBS];
  ushort_t* dst[NJOBS];
  int n_real[NJOBS];
  int n_tot[NJOBS];
  int blk_off[NJOBS + 1];
};
__global__ __launch_bounds__(256) void cvt_jobs_kernel(CvtJobs J) {
  int blk = blockIdx.x;
  int j = 0;
  while (j < NJOBS - 1 && blk >= J.blk_off[j + 1]) ++j;
  int i4 = (blk - J.blk_off[j]) * 256 + threadIdx.x;
  if (i4 * 4 >= J.n_tot[j]) return;
  ushort4 o;
  if (i4 * 4 < J.n_real[j]) {
    float4 v = ((const float4*)J.src[j])[i4];
    o = make_ushort4(f2bf(v.x), f2bf(v.y), f2bf(v.z), f2bf(v.w));
  } else {
    o = make_ushort4(0, 0, 0, 0);
  }
  ((ushort4*)J.dst[j])[i4] = o;
}

// ---------------- MFMA NT GEMM: C = act(alpha*A@W^T + bias) ----------------
// A: [M,K] bf16 (lda), W: [Npad,K] bf16 (ldw, rows padded to 128-mult, zero
// fill), C per CMODE: 0 = fp32 [M,N] ldc; 1 = bf16 [M,N] ldc;
// 2 = bf16 transposed per-batch-of-S-rows: C[bb*sCb + n*ldc + s].
// Batched over blockIdx.z with (zb,zh)=(z/nh, z%nh) strides (elements).
// 128x128 tile, 4 waves (2x2), BK=32, global_load_lds width 16.
template <int ACT, int CMODE>
__global__ __launch_bounds__(256) void gemm_nt_mfma(
    const ushort_t* __restrict__ A, const ushort_t* __restrict__ W,
    const float* __restrict__ bias, void* __restrict__ Cv,
    int N, int K, int lda, int ldw, int ldc, float alpha, int nh,
    long long sAb, long long sAh, long long sWb, long long sWh,
    long long sCb, long long sCh) {
  __shared__ __align__(16) ushort_t As[128 * 32];
  __shared__ __align__(16) ushort_t Bs[128 * 32];
  const int z = blockIdx.z;
  const int zb = z / nh, zh = z - zb * nh;
  A += zb * sAb + zh * sAh;
  W += zb * sWb + zh * sWh;
  const int t = threadIdx.x;
  const int m0 = blockIdx.y * 128, n0 = blockIdx.x * 128;
  const int lane = t & 63, wid = t >> 6;
  const int wr = wid >> 1, wc = wid & 1;
  const int lrow = lane & 15, lk = lane >> 4;

  f32x4 acc[4][4];
#pragma unroll
  for (int i = 0; i < 4; ++i)
#pragma unroll
    for (int j = 0; j < 4; ++j) acc[i][j] = (f32x4){0.f, 0.f, 0.f, 0.f};

  const int srow = t >> 2, sch = (t & 3) * 8;
  const ushort_t* Ag = A + (size_t)(m0 + srow) * lda + sch;
  const ushort_t* Wg = W + (size_t)(n0 + srow) * ldw + sch;
  ushort_t* Al = As + t * 8;
  ushort_t* Bl = Bs + t * 8;
  const size_t a64 = (size_t)64 * lda, w64 = (size_t)64 * ldw;

  for (int k0 = 0; k0 < K; k0 += 32) {
    if (k0) __syncthreads();
    glds16(Ag + k0, Al);
    glds16(Ag + k0 + a64, Al + 2048);
    glds16(Wg + k0, Bl);
    glds16(Wg + k0 + w64, Bl + 2048);
    __syncthreads();
    short8 av[4], bv[4];
#pragma unroll
    for (int i = 0; i < 4; ++i) {
      av[i] = *(const short8*)&As[(wr * 64 + i * 16 + lrow) * 32 + lk * 8];
      bv[i] = *(const short8*)&Bs[(wc * 64 + i * 16 + lrow) * 32 + lk * 8];
    }
#pragma unroll
    for (int i = 0; i < 4; ++i)
#pragma unroll
      for (int j = 0; j < 4; ++j)
        acc[i][j] = __builtin_amdgcn_mfma_f32_16x16x32_bf16(av[i], bv[j],
                                                            acc[i][j], 0, 0, 0);
  }

  if (CMODE == 2) {
    const int bb = m0 / S;
    ushort_t* Cb = (ushort_t*)Cv + (size_t)bb * sCb;
    const int sb = m0 - bb * S + wr * 64;
#pragma unroll
    for (int i = 0; i < 4; ++i) {
      const int s0 = sb + i * 16 + lk * 4;
#pragma unroll
      for (int j = 0; j < 4; ++j) {
        const int n = n0 + wc * 64 + j * 16 + lrow;
        ushort4 o = make_ushort4(f2bf(acc[i][j][0]), f2bf(acc[i][j][1]),
                                 f2bf(acc[i][j][2]), f2bf(acc[i][j][3]));
        *(ushort4*)(Cb + (size_t)n * ldc + s0) = o;
      }
    }
  } else {
    float* Cf = (float*)Cv + zb * sCb + zh * sCh;
    ushort_t* Cu = (ushort_t*)Cv + zb * sCb + zh * sCh;
#pragma unroll
    for (int j = 0; j < 4; ++j) {
      const int n = n0 + wc * 64 + j * 16 + lrow;
      if (n < N) {
        const float vb = bias ? bias[n] : 0.f;
#pragma unroll
        for (int i = 0; i < 4; ++i) {
          const int m = m0 + wr * 64 + i * 16 + lk * 4;
#pragma unroll
          for (int e = 0; e < 4; ++e) {
            float v = alpha * acc[i][j][e] + vb;
            if (ACT == 1) v = fmaxf(v, 0.f);
            if (CMODE == 0) Cf[(size_t)(m + e) * ldc + n] = v;
            else            Cu[(size_t)(m + e) * ldc + n] = f2bf(v);
          }
        }
      }
    }
  }
}

// ---------------- adj bmm: acc[b] = sum_r relu(adj[b,r] @ hr[b,r]) ----------------
// adj: bf16 [B,9,S,S]; hrt: bf16 [B,9,H,S] (hr transposed); Cacc fp32 [B,S,H].
// Relations looped in-kernel with register accumulate (single C write).
__global__ __launch_bounds__(256) void adj_bmm_kernel(
    const ushort_t* __restrict__ adjb, const ushort_t* __restrict__ hrt,
    float* __restrict__ Cacc) {
  __shared__ __align__(16) ushort_t As[128 * 32];
  __shared__ __align__(16) ushort_t Bs[128 * 32];
  const int b = blockIdx.z;
  const int t = threadIdx.x;
  const int m0 = blockIdx.y * 128, n0 = blockIdx.x * 128;
  const int lane = t & 63, wid = t >> 6;
  const int wr = wid >> 1, wc = wid & 1;
  const int lrow = lane & 15, lk = lane >> 4;
  const int srow = t >> 2, sch = (t & 3) * 8;
  ushort_t* Al = As + t * 8;
  ushort_t* Bl = Bs + t * 8;

  float mac[4][4][4];
#pragma unroll
  for (int i = 0; i < 4; ++i)
#pragma unroll
    for (int j = 0; j < 4; ++j)
#pragma unroll
      for (int e = 0; e < 4; ++e) mac[i][j][e] = 0.f;

  for (int r = 0; r < 9; ++r) {
    const ushort_t* Ag = adjb + ((size_t)(b * 9 + r) * S + m0 + srow) * S + sch;
    const ushort_t* Wg = hrt + ((size_t)(b * 9 + r) * H + n0 + srow) * S + sch;
    f32x4 acc[4][4];
#pragma unroll
    for (int i = 0; i < 4; ++i)
#pragma unroll
      for (int j = 0; j < 4; ++j) acc[i][j] = (f32x4){0.f, 0.f, 0.f, 0.f};

    for (int k0 = 0; k0 < S; k0 += 32) {
      __syncthreads();
      glds16(Ag + k0, Al);
      glds16(Ag + k0 + 64 * S, Al + 2048);
      glds16(Wg + k0, Bl);
      glds16(Wg + k0 + 64 * S, Bl + 2048);
      __syncthreads();
      short8 av[4], bv[4];
#pragma unroll
      for (int i = 0; i < 4; ++i) {
        av[i] = *(const short8*)&As[(wr * 64 + i * 16 + lrow) * 32 + lk * 8];
        bv[i] = *(const short8*)&Bs[(wc * 64 + i * 16 + lrow) * 32 + lk * 8];
      }
#pragma unroll
      for (int i = 0; i < 4; ++i)
#pragma unroll
        for (int j = 0; j < 4; ++j)
          acc[i][j] = __builtin_amdgcn_mfma_f32_16x16x32_bf16(av[i], bv[j],
                                                              acc[i][j], 0, 0, 0);
    }
#pragma unroll
    for (int i = 0; i < 4; ++i)
#pragma unroll
      for (int j = 0; j < 4; ++j)
#pragma unroll
        for (int e = 0; e < 4; ++e)
          mac[i][j][e] += fmaxf(acc[i][j][e], 0.f);
  }

#pragma unroll
  for (int i = 0; i < 4; ++i)
#pragma unroll
    for (int j = 0; j < 4; ++j)
#pragma unroll
      for (int e = 0; e < 4; ++e) {
        const int m = m0 + wr * 64 + i * 16 + lk * 4 + e;
        const int n = n0 + wc * 64 + j * 16 + lrow;
        Cacc[((size_t)b * S + m) * H + n] = mac[i][j][e];
      }
}

// ---------------- symmetrize (lower <- upper), fp32 in place ----------------
__global__ __launch_bounds__(384) void symmetrize_kernel(float* __restrict__ Mt) {
  int bhi = blockIdx.x;
  int mat = bhi / S, i = bhi % S;
  int j = threadIdx.x;
  float* base = Mt + (size_t)mat * S * S;
  if (j < i) base[(size_t)i * S + j] = base[(size_t)j * S + i];
}

// ---------------- softmax row + (att!=0) mask -> bf16 adj ----------------
__global__ __launch_bounds__(128) void softmax_mask_kernel(
    const float* __restrict__ Mt, ushort_t* __restrict__ adjb) {
  __shared__ float red[128];
  int row = blockIdx.x;                // B*9*S rows
  const float* r = Mt + (size_t)row * S;
  ushort_t* o = adjb + (size_t)row * S;
  int t = threadIdx.x;
  float v[3];
  float mx = -INFINITY;
#pragma unroll
  for (int q = 0; q < 3; ++q) { v[q] = r[t + q * 128]; mx = fmaxf(mx, v[q]); }
  red[t] = mx; __syncthreads();
  for (int off = 64; off > 0; off >>= 1) {
    if (t < off) red[t] = fmaxf(red[t], red[t + off]);
    __syncthreads();
  }
  mx = red[0]; __syncthreads();
  float e[3], s = 0.f;
#pragma unroll
  for (int q = 0; q < 3; ++q) { e[q] = expf(v[q] - mx); s += e[q]; }
  red[t] = s; __syncthreads();
  for (int off = 64; off > 0; off >>= 1) {
    if (t < off) red[t] += red[t + off];
    __syncthreads();
  }
  float invs = 1.f / red[0];
#pragma unroll
  for (int q = 0; q < 3; ++q)
    o[t + q * 128] = f2bf((v[q] != 0.f) ? e[q] * invs : 0.f);
}

// ---------------- RGAT finalize: feat = LN(relu(acc)/9), fp32 + bf16 out ----------------
__global__ __launch_bounds__(256) void ln_finalize_kernel(
    const float* __restrict__ acc, float* __restrict__ feat,
    ushort_t* __restrict__ featb) {
  __shared__ float red[256];
  int row = blockIdx.x;
  const float* a = acc + (size_t)row * H;
  float* f = feat + (size_t)row * H;
  ushort_t* fb = featb + (size_t)row * H;
  int t = threadIdx.x;
  float v[3];
  float s = 0.f;
#pragma unroll
  for (int q = 0; q < 3; ++q) { v[q] = fmaxf(a[t + q * 256], 0.f) / 9.0f; s += v[q]; }
  red[t] = s; __syncthreads();
  for (int off = 128; off > 0; off >>= 1) {
    if (t < off) red[t] += red[t + off];
    __syncthreads();
  }
  float mean = red[0] / (float)H; __syncthreads();
  float s2 = 0.f;
#pragma unroll
  for (int q = 0; q < 3; ++q) { float d = v[q] - mean; s2 += d * d; }
  red[t] = s2; __syncthreads();
  for (int off = 128; off > 0; off >>= 1) {
    if (t < off) red[t] += red[t + off];
    __syncthreads();
  }
  float var = red[0] / (float)H;
  float rs = rsqrtf(var + 1e-5f);
#pragma unroll
  for (int q = 0; q < 3; ++q) {
    float o = (v[q] - mean) * rs;
    f[t + q * 256] = o;
    fb[t + q * 256] = f2bf(o);
  }
}

// ---------------- concat [x, feat] -> bf16 inp [BS, 1536] ----------------
__global__ __launch_bounds__(256) void concat_kernel(
    const float* __restrict__ x, const float* __restrict__ feat,
    ushort_t* __restrict__ inp) {
  int idx = blockIdx.x * blockDim.x + threadIdx.x;  // BS*192 float4 groups
  if (idx >= BS * (H / 4)) return;
  int bs = idx / (H / 4), c4 = idx - bs * (H / 4);
  float4 vx = ((const float4*)x)[idx];
  float4 vf = ((const float4*)feat)[idx];
  ((ushort4*)inp)[(size_t)bs * (2 * H / 4) + c4] =
      make_ushort4(f2bf(vx.x), f2bf(vx.y), f2bf(vx.z), f2bf(vx.w));
  ((ushort4*)inp)[(size_t)bs * (2 * H / 4) + (H / 4) + c4] =
      make_ushort4(f2bf(vf.x), f2bf(vf.y), f2bf(vf.z), f2bf(vf.w));
}

// ---------------- triu gather ----------------
__global__ __launch_bounds__(384) void gather_kernel(
    const float* __restrict__ src, float* __restrict__ out,
    int nh_src, int hc, int cbase, int do_relu) {
  int bi = blockIdx.x;
  int b = bi / S, i = bi % S;
  int j = threadIdx.x;
  if (j < i) return;
  long long p = (long long)i * S - (long long)i * (i - 1) / 2 + (j - i);
  float* o = out + ((size_t)b * PAIRS + p) * 16 + cbase;
  for (int h = 0; h < hc; ++h) {
    float v = src[(((size_t)b * nh_src + h) * S + i) * S + j];
    if (do_relu) v = fmaxf(v, 0.f);
    o[h] = v;
  }
}

// ---------------- launch ----------------
extern "C" void kernel_launch(void* const* d_in, const int* in_sizes, int n_in,
                              void* d_out, int out_size, void* d_ws, size_t ws_size,
                              hipStream_t stream) {
  (void)in_sizes; (void)n_in; (void)out_size; (void)ws_size;
  const float* x          = (const float*)d_in[0];
  const float* mask       = (const float*)d_in[1];
  const float* wq4gt_w    = (const float*)d_in[2];
  const float* wq4gt_b    = (const float*)d_in[3];
  const float* wk4gt_w    = (const float*)d_in[4];
  const float* wk4gt_b    = (const float*)d_in[5];
  const float* wq4g_rep_w = (const float*)d_in[6];
  const float* wq4g_rep_b = (const float*)d_in[7];
  const float* wq4g_sc_w  = (const float*)d_in[8];
  const float* wq4g_sc_b  = (const float*)d_in[9];
  const float* wk4g_rep_w = (const float*)d_in[10];
  const float* wk4g_rep_b = (const float*)d_in[11];
  const float* wk4g_sc_w  = (const float*)d_in[12];
  const float* wk4g_sc_b  = (const float*)d_in[13];
  const float* rgat_w     = (const float*)d_in[14];
  const float* wq4t_w     = (const float*)d_in[15];
  const float* wq4t_b     = (const float*)d_in[16];
  const float* wk4t_w     = (const float*)d_in[17];
  const float* wk4t_b     = (const float*)d_in[18];
  const float* wq_rep_w   = (const float*)d_in[19];
  const float* wq_rep_b   = (const float*)d_in[20];
  const float* wq_sc_w    = (const float*)d_in[21];
  const float* wq_sc_b    = (const float*)d_in[22];
  const float* wk_rep_w   = (const float*)d_in[23];
  const float* wk_rep_b   = (const float*)d_in[24];
  const float* wk_sc_w    = (const float*)d_in[25];
  const float* wk_sc_b    = (const float*)d_in[26];
  float* out = (float*)d_out;

  // ---- workspace carve-up (256B aligned) ----
  char* wsb = (char*)d_ws;
  size_t off = 0;
  auto af = [&](size_t n) { float* p = (float*)(wsb + off);
                            off += ((n * 4 + 255) & ~(size_t)255); return p; };
  auto au = [&](size_t n) { ushort_t* p = (ushort_t*)(wsb + off);
                            off += ((n * 2 + 255) & ~(size_t)255); return p; };

  float* t_rope = af(24576);
  float* t_qk   = af((size_t)BS * 576);           // fp32 proj out; alias t_sct
  float* t_scg  = af((size_t)B * 9 * S * S);      // g-score fp32 / hr_t bf16 / p-score fp32
  float* t_acc  = af((size_t)BS * H);
  float* t_feat = af((size_t)BS * H);
  ushort_t* xb    = au((size_t)BS * H);
  ushort_t* featb = au((size_t)BS * H);
  ushort_t* inpb  = au((size_t)BS * 2 * H);
  ushort_t* repb  = au((size_t)BS * 960);
  ushort_t* qb    = au((size_t)BS * 576);
  ushort_t* kb    = au((size_t)BS * 576);
  ushort_t* adjb  = au((size_t)B * 9 * S * S);
  ushort_t* wq4gtb   = au(98304);
  ushort_t* wk4gtb   = au(98304);
  ushort_t* wq4g_repb = au(589824);
  ushort_t* wk4g_repb = au(589824);
  ushort_t* wq4g_scb  = au(430080);
  ushort_t* wk4g_scb  = au(430080);
  ushort_t* rgatb     = au(10616832);
  ushort_t* wq4tb     = au(196608);
  ushort_t* wk4tb     = au(196608);
  ushort_t* wq_repb   = au(1572864);
  ushort_t* wk_repb   = au(1572864);
  ushort_t* wq_scb    = au(368640);
  ushort_t* wk_scb    = au(368640);

  float* t_sct = t_qk;                       // [B,S,S] fp32, alias
  ushort_t* hr_t = (ushort_t*)t_scg;         // [B,9,H,S] bf16, alias

  rope_table_kernel<<<S, 32, 0, stream>>>(t_rope);

  // ---- bulk convert weights (+x) to bf16, pad N rows to 128-multiples ----
  {
    CvtJobs J;
    const float* srcs[NJOBS] = {wq4gt_w, wk4gt_w, wq4g_rep_w, wk4g_rep_w,
                                wq4g_sc_w, wk4g_sc_w, rgat_w, wq4t_w, wk4t_w,
                                wq_rep_w, wk_rep_w, wq_sc_w, wk_sc_w, x};
    ushort_t* dsts[NJOBS] = {wq4gtb, wk4gtb, wq4g_repb, wk4g_repb,
                             wq4g_scb, wk4g_scb, rgatb, wq4tb, wk4tb,
                             wq_repb, wk_repb, wq_scb, wk_scb, xb};
    int nreal[NJOBS] = {49152, 49152, 516096, 516096, 387072, 387072,
                        10616832, 98304, 98304, 1474560, 1474560,
                        368640, 368640, 4718592};
    int ntot[NJOBS]  = {98304, 98304, 589824, 589824, 430080, 430080,
                        10616832, 196608, 196608, 1572864, 1572864,
                        368640, 368640, 4718592};
    int acc_blk = 0;
    for (int j = 0; j < NJOBS; ++j) {
      J.src[j] = srcs[j]; J.dst[j] = dsts[j];
      J.n_real[j] = nreal[j]; J.n_tot[j] = ntot[j];
      J.blk_off[j] = acc_blk;
      acc_blk += (ntot[j] + 1023) / 1024;
    }
    J.blk_off[NJOBS] = acc_blk;
    cvt_jobs_kernel<<<acc_blk, 256, 0, stream>>>(J);
  }

  auto rope = [&](const float* src, ushort_t* dst, int nh) {
    int total = BS * nh * 32;
    rope_cvt_kernel<<<(total + 255) / 256, 256, 0, stream>>>(src, dst, mask, t_rope, nh);
  };

  // ---- graph layer: token-pair head (thr_g, ch 15) ----
  gemm_nt_mfma<0, 0><<<dim3(1, 48, 1), 256, 0, stream>>>(
      xb, wq4gtb, wq4gt_b, t_qk, 64, H, H, H, 64, 1.f, 1, 0, 0, 0, 0, 0, 0);
  rope(t_qk, qb, 1);
  gemm_nt_mfma<0, 0><<<dim3(1, 48, 1), 256, 0, stream>>>(
      xb, wk4gtb, wk4gt_b, t_qk, 64, H, H, H, 64, 1.f, 1, 0, 0, 0, 0, 0, 0);
  rope(t_qk, kb, 1);
  gemm_nt_mfma<0, 0><<<dim3(3, 3, B), 256, 0, stream>>>(
      qb, kb, nullptr, t_sct, S, 64, 64, 64, S, INV, 1,
      (long long)S * 64, 0, (long long)S * 64, 0, (long long)S * S, 0);
  gather_kernel<<<BS, 384, 0, stream>>>(t_sct, out, 1, 1, 15, 1);

  // ---- graph layer: 9-head score (sc_g ch 7..14) + adj ----
  gemm_nt_mfma<1, 1><<<dim3(6, 48, 1), 256, 0, stream>>>(
      xb, wq4g_repb, wq4g_rep_b, repb, 672, H, H, H, 672, 1.f, 1, 0, 0, 0, 0, 0, 0);
  gemm_nt_mfma<0, 0><<<dim3(5, 48, 1), 256, 0, stream>>>(
      repb, wq4g_scb, wq4g_sc_b, t_qk, 576, 672, 672, 672, 576, 1.f, 1, 0, 0, 0, 0, 0, 0);
  rope(t_qk, qb, 9);
  gemm_nt_mfma<1, 1><<<dim3(6, 48, 1), 256, 0, stream>>>(
      xb, wk4g_repb, wk4g_rep_b, repb, 672, H, H, H, 672, 1.f, 1, 0, 0, 0, 0, 0, 0);
  gemm_nt_mfma<0, 0><<<dim3(5, 48, 1), 256, 0, stream>>>(
      repb, wk4g_scb, wk4g_sc_b, t_qk, 576, 672, 672, 672, 576, 1.f, 1, 0, 0, 0, 0, 0, 0);
  rope(t_qk, kb, 9);
  gemm_nt_mfma<0, 0><<<dim3(3, 3, B * 9), 256, 0, stream>>>(
      qb, kb, nullptr, t_scg, S, 64, 576, 576, S, INV, 9,
      (long long)S * 576, 64, (long long)S * 576, 64,
      (long long)9 * S * S, (long long)S * S);
  gather_kernel<<<BS, 384, 0, stream>>>(t_scg, out, 9, 8, 7, 0);
  symmetrize_kernel<<<B * 9 * S, 384, 0, stream>>>(t_scg);
  softmax_mask_kernel<<<B * 9 * S, 128, 0, stream>>>(t_scg, adjb);

  // ---- RGAT x2 ----
  const ushort_t* fsrc = xb;
  for (int l = 0; l < 2; ++l) {
    gemm_nt_mfma<0, 2><<<dim3(54, 48, 1), 256, 0, stream>>>(
        fsrc, rgatb + (size_t)l * 9 * H * H, nullptr, hr_t,
        9 * H, H, H, H, S, 1.f, 1, 0, 0, 0, 0, (long long)9 * H * S, 0);
    adj_bmm_kernel<<<dim3(6, 3, B), 256, 0, stream>>>(adjb, hr_t, t_acc);
    ln_finalize_kernel<<<BS, 256, 0, stream>>>(t_acc, t_feat, featb);
    fsrc = featb;
  }

  // ---- prediction head ----
  concat_kernel<<<(BS * (H / 4) + 255) / 256, 256, 0, stream>>>(x, t_feat, inpb);

  gemm_nt_mfma<0, 0><<<dim3(1, 48, 1), 256, 0, stream>>>(
      inpb, wq4tb, wq4t_b, t_qk, 64, 2 * H, 2 * H, 2 * H, 64, 1.f, 1, 0, 0, 0, 0, 0, 0);
  rope(t_qk, qb, 1);
  gemm_nt_mfma<0, 0><<<dim3(1, 48, 1), 256, 0, stream>>>(
      inpb, wk4tb, wk4t_b, t_qk, 64, 2 * H, 2 * H, 2 * H, 64, 1.f, 1, 0, 0, 0, 0, 0, 0);
  rope(t_qk, kb, 1);
  gemm_nt_mfma<0, 0><<<dim3(3, 3, B), 256, 0, stream>>>(
      qb, kb, nullptr, t_sct, S, 64, 64, 64, S, INV, 1,
      (long long)S * 64, 0, (long long)S * 64, 0, (long long)S * S, 0);
  gather_kernel<<<BS, 384, 0, stream>>>(t_sct, out, 1, 1, 6, 1);

  gemm_nt_mfma<1, 1><<<dim3(8, 48, 1), 256, 0, stream>>>(
      inpb, wq_repb, wq_rep_b, repb, 960, 2 * H, 2 * H, 2 * H, 960, 1.f, 1, 0, 0, 0, 0, 0, 0);
  gemm_nt_mfma<0, 0><<<dim3(3, 48, 1), 256, 0, stream>>>(
      repb, wq_scb, wq_sc_b, t_qk, 384, 960, 960, 960, 384, 1.f, 1, 0, 0, 0, 0, 0, 0);
  rope(t_qk, qb, 6);
  gemm_nt_mfma<1, 1><<<dim3(8, 48, 1), 256, 0, stream>>>(
      inpb, wk_repb, wk_rep_b, repb, 960, 2 * H, 2 * H, 2 * H, 960, 1.f, 1, 0, 0, 0, 0, 0, 0);
  gemm_nt_mfma<0, 0><<<dim3(3, 48, 1), 256, 0, stream>>>(
      repb, wk_scb, wk_sc_b, t_qk, 384, 960, 960, 960, 384, 1.f, 1, 0, 0, 0, 0, 0, 0);
  rope(t_qk, kb, 6);
  gemm_nt_mfma<0, 0><<<dim3(3, 3, B * 6), 256, 0, stream>>>(
      qb, kb, nullptr, t_scg, S, 64, 384, 384, S, INV, 6,
      (long long)S * 384, 64, (long long)S * 384, 64,
      (long long)6 * S * S, (long long)S * S);
  gather_kernel<<<BS, 384, 0, stream>>>(t_scg, out, 6, 6, 0, 0);
}

// Round 4
// 1004.615 us; speedup vs baseline: 5.4017x; 1.2465x over previous
//
#include <hip/hip_runtime.h>
#include <math.h>

typedef unsigned short ushort_t;
typedef __attribute__((ext_vector_type(8))) short short8;
typedef __attribute__((ext_vector_type(4))) float f32x4;

// ---------------- problem constants ----------------
constexpr int B = 16, S = 384, H = 768;
constexpr int BS = B * S;                                // 6144
constexpr long long PAIRS = (long long)S * (S + 1) / 2;  // 73920
constexpr float INV = 0.125f;                            // 1/sqrt(64)

__device__ __forceinline__ ushort_t f2bf(float f) {
  unsigned int u = __float_as_uint(f);
  u += 0x7FFF + ((u >> 16) & 1);       // round-to-nearest-even
  return (ushort_t)(u >> 16);
}

__device__ __forceinline__ void glds16(const ushort_t* g, ushort_t* l) {
  __builtin_amdgcn_global_load_lds(
      (const __attribute__((address_space(1))) unsigned int*)g,
      (__attribute__((address_space(3))) unsigned int*)l, 16, 0, 0);
}

// ---------------- rope table ----------------
__global__ void rope_table_kernel(float* tab) {
  int s = blockIdx.x, i = threadIdx.x;  // 384 x 32
  double ang = (double)s / pow(10000.0, (double)i / 32.0);
  tab[s * 64 + 2 * i]     = (float)cos(ang);
  tab[s * 64 + 2 * i + 1] = (float)sin(ang);
}

// ---------------- rope + mask: fp32 src -> bf16 dst ----------------
__global__ __launch_bounds__(256) void rope_cvt_kernel(
    const float* __restrict__ src, ushort_t* __restrict__ dst,
    const float* __restrict__ mask, const float* __restrict__ tab, int nh) {
  int idx = blockIdx.x * blockDim.x + threadIdx.x;
  int total = BS * nh * 32;
  if (idx >= total) return;
  int i  = idx & 31;
  int h  = (idx >> 5) % nh;
  int bs = idx / (32 * nh);
  int s  = bs % S;
  float c  = tab[s * 64 + 2 * i];
  float sn = tab[s * 64 + 2 * i + 1];
  float m  = mask[bs];
  size_t o = (size_t)bs * (nh * 64) + h * 64 + 2 * i;
  float x0 = src[o], x1 = src[o + 1];
  dst[o]     = f2bf(m * (x0 * c - x1 * sn));
  dst[o + 1] = f2bf(m * (x1 * c + x0 * sn));
}

// ---------------- bulk fp32 -> bf16 convert with row padding ----------------
constexpr int NJOBS = 14;
struct CvtJobs {
  const float* src[NJOBS];
  ushort_t* dst[NJOBS];
  int n_real[NJOBS];
  int n_tot[NJOBS];
  int blk_off[NJOBS + 1];
};
__global__ __launch_bounds__(256) void cvt_jobs_kernel(CvtJobs J) {
  int blk = blockIdx.x;
  int j = 0;
  while (j < NJOBS - 1 && blk >= J.blk_off[j + 1]) ++j;
  int i4 = (blk - J.blk_off[j]) * 256 + threadIdx.x;
  if (i4 * 4 >= J.n_tot[j]) return;
  ushort4 o;
  if (i4 * 4 < J.n_real[j]) {
    float4 v = ((const float4*)J.src[j])[i4];
    o = make_ushort4(f2bf(v.x), f2bf(v.y), f2bf(v.z), f2bf(v.w));
  } else {
    o = make_ushort4(0, 0, 0, 0);
  }
  ((ushort4*)J.dst[j])[i4] = o;
}

// ---------------- MFMA NT GEMM, 2-phase pipelined ----------------
// A: [M,K] bf16 (lda), W: [Npad,K] bf16 (ldw, rows zero-padded to 128-mult).
// CMODE 0: fp32 C[M,N] ldc.  1: bf16 C[M,N] ldc.
// 2: bf16 transposed per-batch-of-S rows: C[bb*sCb + n*ldc + s].
// 3: triu-gather only: gout[(zb*PAIRS+p)*16 + cbase + zh] (p from (m,n), n>=m).
// 4: fp32 matrix (ldc) AND triu-gather for zh<8 at cbase+zh.
// Batched over blockIdx.z, (zb,zh)=(z/nh,z%nh). 128x128 tile, 4 waves, BK=32.
template <int ACT, int CMODE, int SWZ>
__global__ __launch_bounds__(256) void gemm_nt_mfma(
    const ushort_t* __restrict__ A, const ushort_t* __restrict__ W,
    const float* __restrict__ bias, void* __restrict__ Cv,
    float* __restrict__ gout, int cbase,
    int N, int K, int lda, int ldw, int ldc, float alpha, int nh,
    long long sAb, long long sAh, long long sWb, long long sWh,
    long long sCb, long long sCh) {
  __shared__ __align__(16) ushort_t As[2][128 * 32];
  __shared__ __align__(16) ushort_t Bs[2][128 * 32];
  int bx = blockIdx.x, by = blockIdx.y, bz = blockIdx.z;
  if (SWZ) {   // bijective XCD swizzle; requires nwg % 8 == 0 (all our grids)
    int nx = gridDim.x, ny = gridDim.y;
    int nwg = nx * ny * gridDim.z;
    int flat = bx + nx * (by + ny * bz);
    int l = (flat & 7) * (nwg >> 3) + (flat >> 3);
    bx = l % nx; l /= nx; by = l % ny; bz = l / ny;
  }
  const int zb = bz / nh, zh = bz - zb * nh;
  A += zb * sAb + zh * sAh;
  W += zb * sWb + zh * sWh;
  const int t = threadIdx.x;
  const int m0 = by * 128, n0 = bx * 128;
  const int lane = t & 63, wid = t >> 6;
  const int wr = wid >> 1, wc = wid & 1;
  const int lrow = lane & 15, lk = lane >> 4;
  const int srow = t >> 2, sch = (t & 3) * 8;
  const ushort_t* Ag = A + (size_t)(m0 + srow) * lda + sch;
  const ushort_t* Wg = W + (size_t)(n0 + srow) * ldw + sch;
  const size_t a64 = (size_t)64 * lda, w64 = (size_t)64 * ldw;

  f32x4 acc[4][4];
#pragma unroll
  for (int i = 0; i < 4; ++i)
#pragma unroll
    for (int j = 0; j < 4; ++j) acc[i][j] = (f32x4){0.f, 0.f, 0.f, 0.f};

  auto stage = [&](int k0, int buf) {
    glds16(Ag + k0, &As[buf][t * 8]);
    glds16(Ag + k0 + a64, &As[buf][2048 + t * 8]);
    glds16(Wg + k0, &Bs[buf][t * 8]);
    glds16(Wg + k0 + w64, &Bs[buf][2048 + t * 8]);
  };

  const int nk = K >> 5;
  stage(0, 0);
  for (int s = 0; s < nk; ++s) {
    __syncthreads();                       // stage(s) visible; prev reads done
    if (s + 1 < nk) stage((s + 1) << 5, (s + 1) & 1);
    const int buf = s & 1;
    short8 av[4], bv[4];
#pragma unroll
    for (int i = 0; i < 4; ++i) {
      av[i] = *(const short8*)&As[buf][(wr * 64 + i * 16 + lrow) * 32 + lk * 8];
      bv[i] = *(const short8*)&Bs[buf][(wc * 64 + i * 16 + lrow) * 32 + lk * 8];
    }
#pragma unroll
    for (int i = 0; i < 4; ++i)
#pragma unroll
      for (int j = 0; j < 4; ++j)
        acc[i][j] = __builtin_amdgcn_mfma_f32_16x16x32_bf16(av[i], bv[j],
                                                            acc[i][j], 0, 0, 0);
  }

  if (CMODE == 2) {
    const int bb = m0 / S;
    ushort_t* Cb = (ushort_t*)Cv + (size_t)bb * sCb;
    const int sb = m0 - bb * S + wr * 64;
#pragma unroll
    for (int i = 0; i < 4; ++i) {
      const int s0 = sb + i * 16 + lk * 4;
#pragma unroll
      for (int j = 0; j < 4; ++j) {
        const int n = n0 + wc * 64 + j * 16 + lrow;
        ushort4 o = make_ushort4(f2bf(acc[i][j][0]), f2bf(acc[i][j][1]),
                                 f2bf(acc[i][j][2]), f2bf(acc[i][j][3]));
        *(ushort4*)(Cb + (size_t)n * ldc + s0) = o;
      }
    }
  } else if (CMODE == 3) {
#pragma unroll
    for (int j = 0; j < 4; ++j) {
      const int n = n0 + wc * 64 + j * 16 + lrow;
#pragma unroll
      for (int i = 0; i < 4; ++i) {
#pragma unroll
        for (int e = 0; e < 4; ++e) {
          const int m = m0 + wr * 64 + i * 16 + lk * 4 + e;
          if (n >= m) {
            long long p = (long long)m * S - (long long)m * (m - 1) / 2 + (n - m);
            float v = alpha * acc[i][j][e];
            if (ACT == 1) v = fmaxf(v, 0.f);
            gout[((size_t)zb * PAIRS + p) * 16 + cbase + zh] = v;
          }
        }
      }
    }
  } else if (CMODE == 4) {
    float* Cf = (float*)Cv + zb * sCb + zh * sCh;
#pragma unroll
    for (int j = 0; j < 4; ++j) {
      const int n = n0 + wc * 64 + j * 16 + lrow;
#pragma unroll
      for (int i = 0; i < 4; ++i) {
#pragma unroll
        for (int e = 0; e < 4; ++e) {
          const int m = m0 + wr * 64 + i * 16 + lk * 4 + e;
          float v = alpha * acc[i][j][e];
          Cf[(size_t)m * ldc + n] = v;
          if (zh < 8 && n >= m) {
            long long p = (long long)m * S - (long long)m * (m - 1) / 2 + (n - m);
            gout[((size_t)zb * PAIRS + p) * 16 + cbase + zh] = v;
          }
        }
      }
    }
  } else {
    float* Cf = (float*)Cv + zb * sCb + zh * sCh;
    ushort_t* Cu = (ushort_t*)Cv + zb * sCb + zh * sCh;
#pragma unroll
    for (int j = 0; j < 4; ++j) {
      const int n = n0 + wc * 64 + j * 16 + lrow;
      if (n < N) {
        const float vb = bias ? bias[n] : 0.f;
#pragma unroll
        for (int i = 0; i < 4; ++i) {
          const int m = m0 + wr * 64 + i * 16 + lk * 4;
#pragma unroll
          for (int e = 0; e < 4; ++e) {
            float v = alpha * acc[i][j][e] + vb;
            if (ACT == 1) v = fmaxf(v, 0.f);
            if (CMODE == 0) Cf[(size_t)(m + e) * ldc + n] = v;
            else            Cu[(size_t)(m + e) * ldc + n] = f2bf(v);
          }
        }
      }
    }
  }
}

// ---------------- adj bmm: P[rg] = sum_{r in group} relu(adj[b,r] @ hr[b,r]) ----------------
// 3 relation-groups -> 864 blocks. 2-phase pipelined. Partials fp32 [B,S,H].
__global__ __launch_bounds__(256) void adj_bmm_kernel(
    const ushort_t* __restrict__ adjb, const ushort_t* __restrict__ hrt,
    float* __restrict__ P0, float* __restrict__ P1, float* __restrict__ P2) {
  __shared__ __align__(16) ushort_t As[2][128 * 32];
  __shared__ __align__(16) ushort_t Bs[2][128 * 32];
  int bx = blockIdx.x, by = blockIdx.y, bz = blockIdx.z;
  {   // XCD swizzle (nwg = 864, %8==0)
    int nx = gridDim.x, ny = gridDim.y;
    int nwg = nx * ny * gridDim.z;
    int flat = bx + nx * (by + ny * bz);
    int l = (flat & 7) * (nwg >> 3) + (flat >> 3);
    bx = l % nx; l /= nx; by = l % ny; bz = l / ny;
  }
  const int b = bz / 3, rg = bz - b * 3;
  float* P = (rg == 0) ? P0 : (rg == 1) ? P1 : P2;
  const int t = threadIdx.x;
  const int m0 = by * 128, n0 = bx * 128;
  const int lane = t & 63, wid = t >> 6;
  const int wr = wid >> 1, wc = wid & 1;
  const int lrow = lane & 15, lk = lane >> 4;
  const int srow = t >> 2, sch = (t & 3) * 8;

  const ushort_t* adjA =
      adjb + ((size_t)(b * 9 + rg * 3) * S + m0 + srow) * S + sch;
  const ushort_t* hrA =
      hrt + ((size_t)(b * 9 + rg * 3) * H + n0 + srow) * S + sch;

  float mac[4][4][4];
#pragma unroll
  for (int i = 0; i < 4; ++i)
#pragma unroll
    for (int j = 0; j < 4; ++j)
#pragma unroll
      for (int e = 0; e < 4; ++e) mac[i][j][e] = 0.f;

  f32x4 acc[4][4];
#pragma unroll
  for (int i = 0; i < 4; ++i)
#pragma unroll
    for (int j = 0; j < 4; ++j) acc[i][j] = (f32x4){0.f, 0.f, 0.f, 0.f};

  auto stage = [&](int s, int buf) {
    const int rr = s / 12;
    const int k0 = (s - rr * 12) * 32;
    const ushort_t* Ag = adjA + (size_t)rr * S * S + k0;
    const ushort_t* Wg = hrA + (size_t)rr * H * S + k0;
    glds16(Ag, &As[buf][t * 8]);
    glds16(Ag + 64 * S, &As[buf][2048 + t * 8]);
    glds16(Wg, &Bs[buf][t * 8]);
    glds16(Wg + 64 * S, &Bs[buf][2048 + t * 8]);
  };

  stage(0, 0);
  for (int s = 0; s < 36; ++s) {
    __syncthreads();
    if (s + 1 < 36) stage(s + 1, (s + 1) & 1);
    const int buf = s & 1;
    short8 av[4], bv[4];
#pragma unroll
    for (int i = 0; i < 4; ++i) {
      av[i] = *(const short8*)&As[buf][(wr * 64 + i * 16 + lrow) * 32 + lk * 8];
      bv[i] = *(const short8*)&Bs[buf][(wc * 64 + i * 16 + lrow) * 32 + lk * 8];
    }
#pragma unroll
    for (int i = 0; i < 4; ++i)
#pragma unroll
      for (int j = 0; j < 4; ++j)
        acc[i][j] = __builtin_amdgcn_mfma_f32_16x16x32_bf16(av[i], bv[j],
                                                            acc[i][j], 0, 0, 0);
    if ((s % 12) == 11) {   // relation boundary: relu-accumulate, reset
#pragma unroll
      for (int i = 0; i < 4; ++i)
#pragma unroll
        for (int j = 0; j < 4; ++j) {
#pragma unroll
          for (int e = 0; e < 4; ++e)
            mac[i][j][e] += fmaxf(acc[i][j][e], 0.f);
          acc[i][j] = (f32x4){0.f, 0.f, 0.f, 0.f};
        }
    }
  }

#pragma unroll
  for (int i = 0; i < 4; ++i)
#pragma unroll
    for (int j = 0; j < 4; ++j)
#pragma unroll
      for (int e = 0; e < 4; ++e) {
        const int m = m0 + wr * 64 + i * 16 + lk * 4 + e;
        const int n = n0 + wc * 64 + j * 16 + lrow;
        P[((size_t)b * S + m) * H + n] = mac[i][j][e];
      }
}

// ---------------- tiled symmetrize: lower <- upper^T (coalesced) ----------------
__global__ __launch_bounds__(256) void sym_transpose_kernel(float* __restrict__ Mt) {
  __shared__ float T[32][33];
  int tp = blockIdx.x;                 // 0..77 upper-tile pairs (12x13/2)
  int ti = 0;
  { int rem = tp, left = 12;
    while (rem >= left) { rem -= left; ++ti; --left; }
    tp = rem; }
  const int tj = ti + tp;
  float* base = Mt + (size_t)blockIdx.y * S * S;
  const int r = threadIdx.x >> 5, c = threadIdx.x & 31;
#pragma unroll
  for (int k = 0; k < 4; ++k)
    T[r + 8 * k][c] = base[(size_t)(ti * 32 + r + 8 * k) * S + tj * 32 + c];
  __syncthreads();
  if (ti == tj) {
#pragma unroll
    for (int k = 0; k < 4; ++k)
      if ((r + 8 * k) > c)
        base[(size_t)(ti * 32 + r + 8 * k) * S + tj * 32 + c] = T[c][r + 8 * k];
  } else {
#pragma unroll
    for (int k = 0; k < 4; ++k)
      base[(size_t)(tj * 32 + r + 8 * k) * S + ti * 32 + c] = T[c][r + 8 * k];
  }
}

// ---------------- softmax row + (att!=0) mask -> bf16 adj ----------------
__global__ __launch_bounds__(128) void softmax_mask_kernel(
    const float* __restrict__ Mt, ushort_t* __restrict__ adjb) {
  __shared__ float red[128];
  int row = blockIdx.x;                // B*9*S rows
  const float* r = Mt + (size_t)row * S;
  ushort_t* o = adjb + (size_t)row * S;
  int t = threadIdx.x;
  float v[3];
  float mx = -INFINITY;
#pragma unroll
  for (int q = 0; q < 3; ++q) { v[q] = r[t + q * 128]; mx = fmaxf(mx, v[q]); }
  red[t] = mx; __syncthreads();
  for (int off = 64; off > 0; off >>= 1) {
    if (t < off) red[t] = fmaxf(red[t], red[t + off]);
    __syncthreads();
  }
  mx = red[0]; __syncthreads();
  float e[3], s = 0.f;
#pragma unroll
  for (int q = 0; q < 3; ++q) { e[q] = expf(v[q] - mx); s += e[q]; }
  red[t] = s; __syncthreads();
  for (int off = 64; off > 0; off >>= 1) {
    if (t < off) red[t] += red[t + off];
    __syncthreads();
  }
  float invs = 1.f / red[0];
#pragma unroll
  for (int q = 0; q < 3; ++q)
    o[t + q * 128] = f2bf((v[q] != 0.f) ? e[q] * invs : 0.f);
}

// ---------------- RGAT finalize: feat = LN((P0+P1+P2)/9) ----------------
__global__ __launch_bounds__(256) void ln_finalize_kernel(
    const float* __restrict__ P0, const float* __restrict__ P1,
    const float* __restrict__ P2, float* __restrict__ feat,
    ushort_t* __restrict__ featb) {
  __shared__ float red[256];
  int row = blockIdx.x;
  const size_t base = (size_t)row * H;
  float* f = feat + base;
  ushort_t* fb = featb + base;
  int t = threadIdx.x;
  float v[3];
  float s = 0.f;
#pragma unroll
  for (int q = 0; q < 3; ++q) {
    size_t ix = base + t + q * 256;
    v[q] = (P0[ix] + P1[ix] + P2[ix]) / 9.0f;   // terms >= 0, relu is no-op
    s += v[q];
  }
  red[t] = s; __syncthreads();
  for (int off = 128; off > 0; off >>= 1) {
    if (t < off) red[t] += red[t + off];
    __syncthreads();
  }
  float mean = red[0] / (float)H; __syncthreads();
  float s2 = 0.f;
#pragma unroll
  for (int q = 0; q < 3; ++q) { float d = v[q] - mean; s2 += d * d; }
  red[t] = s2; __syncthreads();
  for (int off = 128; off > 0; off >>= 1) {
    if (t < off) red[t] += red[t + off];
    __syncthreads();
  }
  float var = red[0] / (float)H;
  float rs = rsqrtf(var + 1e-5f);
#pragma unroll
  for (int q = 0; q < 3; ++q) {
    float o = (v[q] - mean) * rs;
    f[t + q * 256] = o;
    fb[t + q * 256] = f2bf(o);
  }
}

// ---------------- concat [x, feat] -> bf16 inp [BS, 1536] ----------------
__global__ __launch_bounds__(256) void concat_kernel(
    const float* __restrict__ x, const float* __restrict__ feat,
    ushort_t* __restrict__ inp) {
  int idx = blockIdx.x * blockDim.x + threadIdx.x;  // BS*192 float4 groups
  if (idx >= BS * (H / 4)) return;
  int bs = idx / (H / 4), c4 = idx - bs * (H / 4);
  float4 vx = ((const float4*)x)[idx];
  float4 vf = ((const float4*)feat)[idx];
  ((ushort4*)inp)[(size_t)bs * (2 * H / 4) + c4] =
      make_ushort4(f2bf(vx.x), f2bf(vx.y), f2bf(vx.z), f2bf(vx.w));
  ((ushort4*)inp)[(size_t)bs * (2 * H / 4) + (H / 4) + c4] =
      make_ushort4(f2bf(vf.x), f2bf(vf.y), f2bf(vf.z), f2bf(vf.w));
}

// ---------------- launch ----------------
extern "C" void kernel_launch(void* const* d_in, const int* in_sizes, int n_in,
                              void* d_out, int out_size, void* d_ws, size_t ws_size,
                              hipStream_t stream) {
  (void)in_sizes; (void)n_in; (void)out_size; (void)ws_size;
  const float* x          = (const float*)d_in[0];
  const float* mask       = (const float*)d_in[1];
  const float* wq4gt_w    = (const float*)d_in[2];
  const float* wq4gt_b    = (const float*)d_in[3];
  const float* wk4gt_w    = (const float*)d_in[4];
  const float* wk4gt_b    = (const float*)d_in[5];
  const float* wq4g_rep_w = (const float*)d_in[6];
  const float* wq4g_rep_b = (const float*)d_in[7];
  const float* wq4g_sc_w  = (const float*)d_in[8];
  const float* wq4g_sc_b  = (const float*)d_in[9];
  const float* wk4g_rep_w = (const float*)d_in[10];
  const float* wk4g_rep_b = (const float*)d_in[11];
  const float* wk4g_sc_w  = (const float*)d_in[12];
  const float* wk4g_sc_b  = (const float*)d_in[13];
  const float* rgat_w     = (const float*)d_in[14];
  const float* wq4t_w     = (const float*)d_in[15];
  const float* wq4t_b     = (const float*)d_in[16];
  const float* wk4t_w     = (const float*)d_in[17];
  const float* wk4t_b     = (const float*)d_in[18];
  const float* wq_rep_w   = (const float*)d_in[19];
  const float* wq_rep_b   = (const float*)d_in[20];
  const float* wq_sc_w    = (const float*)d_in[21];
  const float* wq_sc_b    = (const float*)d_in[22];
  const float* wk_rep_w   = (const float*)d_in[23];
  const float* wk_rep_b   = (const float*)d_in[24];
  const float* wk_sc_w    = (const float*)d_in[25];
  const float* wk_sc_b    = (const float*)d_in[26];
  float* out = (float*)d_out;

  // ---- workspace carve-up (256B aligned) ----
  char* wsb = (char*)d_ws;
  size_t off = 0;
  auto af = [&](size_t n) { float* p = (float*)(wsb + off);
                            off += ((n * 4 + 255) & ~(size_t)255); return p; };
  auto au = [&](size_t n) { ushort_t* p = (ushort_t*)(wsb + off);
                            off += ((n * 2 + 255) & ~(size_t)255); return p; };

  float* t_rope = af(24576);
  float* t_qk   = af((size_t)BS * 576);           // fp32 proj out (pre-rope)
  float* t_scg  = af((size_t)B * 9 * S * S);      // g-score fp32 / hr_t bf16
  float* t_acc  = af((size_t)BS * H);             // RGAT partial P0
  float* t_feat = af((size_t)BS * H);
  ushort_t* xb    = au((size_t)BS * H);
  ushort_t* featb = au((size_t)BS * H);
  ushort_t* inpb  = au((size_t)BS * 2 * H);       // P2 alias during RGAT
  ushort_t* repb  = au((size_t)BS * 960);         // P1 alias (spans repb+qb)
  ushort_t* qb    = au((size_t)BS * 576);
  ushort_t* kb    = au((size_t)BS * 576);
  ushort_t* adjb  = au((size_t)B * 9 * S * S);
  ushort_t* wq4gtb   = au(98304);
  ushort_t* wk4gtb   = au(98304);
  ushort_t* wq4g_repb = au(589824);
  ushort_t* wk4g_repb = au(589824);
  ushort_t* wq4g_scb  = au(430080);
  ushort_t* wk4g_scb  = au(430080);
  ushort_t* rgatb     = au(10616832);
  ushort_t* wq4tb     = au(196608);
  ushort_t* wk4tb     = au(196608);
  ushort_t* wq_repb   = au(1572864);
  ushort_t* wk_repb   = au(1572864);
  ushort_t* wq_scb    = au(368640);
  ushort_t* wk_scb    = au(368640);

  ushort_t* hr_t = (ushort_t*)t_scg;         // [B,9,H,S] bf16, alias
  float* P0 = t_acc;                         // each exactly BS*H*4 bytes
  float* P1 = (float*)repb;                  // repb(11.8MB)+qb(7.1MB) region
  float* P2 = (float*)inpb;                  // inpb region (18.9MB)

  rope_table_kernel<<<S, 32, 0, stream>>>(t_rope);

  // ---- bulk convert weights (+x) to bf16, pad N rows to 128-multiples ----
  {
    CvtJobs J;
    const float* srcs[NJOBS] = {wq4gt_w, wk4gt_w, wq4g_rep_w, wk4g_rep_w,
                                wq4g_sc_w, wk4g_sc_w, rgat_w, wq4t_w, wk4t_w,
                                wq_rep_w, wk_rep_w, wq_sc_w, wk_sc_w, x};
    ushort_t* dsts[NJOBS] = {wq4gtb, wk4gtb, wq4g_repb, wk4g_repb,
                             wq4g_scb, wk4g_scb, rgatb, wq4tb, wk4tb,
                             wq_repb, wk_repb, wq_scb, wk_scb, xb};
    int nreal[NJOBS] = {49152, 49152, 516096, 516096, 387072, 387072,
                        10616832, 98304, 98304, 1474560, 1474560,
                        368640, 368640, 4718592};
    int ntot[NJOBS]  = {98304, 98304, 589824, 589824, 430080, 430080,
                        10616832, 196608, 196608, 1572864, 1572864,
                        368640, 368640, 4718592};
    int acc_blk = 0;
    for (int j = 0; j < NJOBS; ++j) {
      J.src[j] = srcs[j]; J.dst[j] = dsts[j];
      J.n_real[j] = nreal[j]; J.n_tot[j] = ntot[j];
      J.blk_off[j] = acc_blk;
      acc_blk += (ntot[j] + 1023) / 1024;
    }
    J.blk_off[NJOBS] = acc_blk;
    cvt_jobs_kernel<<<acc_blk, 256, 0, stream>>>(J);
  }

  auto rope = [&](const float* src, ushort_t* dst, int nh) {
    int total = BS * nh * 32;
    rope_cvt_kernel<<<(total + 255) / 256, 256, 0, stream>>>(src, dst, mask, t_rope, nh);
  };

  // ---- graph layer: token-pair head (thr_g -> out ch 15, fused gather) ----
  gemm_nt_mfma<0, 0, 1><<<dim3(1, 48, 1), 256, 0, stream>>>(
      xb, wq4gtb, wq4gt_b, t_qk, nullptr, 0,
      64, H, H, H, 64, 1.f, 1, 0, 0, 0, 0, 0, 0);
  rope(t_qk, qb, 1);
  gemm_nt_mfma<0, 0, 1><<<dim3(1, 48, 1), 256, 0, stream>>>(
      xb, wk4gtb, wk4gt_b, t_qk, nullptr, 0,
      64, H, H, H, 64, 1.f, 1, 0, 0, 0, 0, 0, 0);
  rope(t_qk, kb, 1);
  gemm_nt_mfma<1, 3, 1><<<dim3(3, 3, B), 256, 0, stream>>>(
      qb, kb, nullptr, nullptr, out, 15,
      S, 64, 64, 64, S, INV, 1,
      (long long)S * 64, 0, (long long)S * 64, 0, 0, 0);

  // ---- graph layer: 9-head score (matrix + fused sc_g ch 7..14) ----
  gemm_nt_mfma<1, 1, 1><<<dim3(6, 48, 1), 256, 0, stream>>>(
      xb, wq4g_repb, wq4g_rep_b, repb, nullptr, 0,
      672, H, H, H, 672, 1.f, 1, 0, 0, 0, 0, 0, 0);
  gemm_nt_mfma<0, 0, 1><<<dim3(5, 48, 1), 256, 0, stream>>>(
      repb, wq4g_scb, wq4g_sc_b, t_qk, nullptr, 0,
      576, 672, 672, 672, 576, 1.f, 1, 0, 0, 0, 0, 0, 0);
  rope(t_qk, qb, 9);
  gemm_nt_mfma<1, 1, 1><<<dim3(6, 48, 1), 256, 0, stream>>>(
      xb, wk4g_repb, wk4g_rep_b, repb, nullptr, 0,
      672, H, H, H, 672, 1.f, 1, 0, 0, 0, 0, 0, 0);
  gemm_nt_mfma<0, 0, 1><<<dim3(5, 48, 1), 256, 0, stream>>>(
      repb, wk4g_scb, wk4g_sc_b, t_qk, nullptr, 0,
      576, 672, 672, 672, 576, 1.f, 1, 0, 0, 0, 0, 0, 0);
  rope(t_qk, kb, 9);
  gemm_nt_mfma<0, 4, 1><<<dim3(3, 3, B * 9), 256, 0, stream>>>(
      qb, kb, nullptr, t_scg, out, 7,
      S, 64, 576, 576, S, INV, 9,
      (long long)S * 576, 64, (long long)S * 576, 64,
      (long long)9 * S * S, (long long)S * S);
  sym_transpose_kernel<<<dim3(78, B * 9), 256, 0, stream>>>(t_scg);
  softmax_mask_kernel<<<B * 9 * S, 128, 0, stream>>>(t_scg, adjb);

  // ---- RGAT x2 ----
  const ushort_t* fsrc = xb;
  for (int l = 0; l < 2; ++l) {
    gemm_nt_mfma<0, 2, 1><<<dim3(54, 48, 1), 256, 0, stream>>>(
        fsrc, rgatb + (size_t)l * 9 * H * H, nullptr, hr_t, nullptr, 0,
        9 * H, H, H, H, S, 1.f, 1, 0, 0, 0, 0, (long long)9 * H * S, 0);
    adj_bmm_kernel<<<dim3(6, 3, B * 3), 256, 0, stream>>>(adjb, hr_t, P0, P1, P2);
    ln_finalize_kernel<<<BS, 256, 0, stream>>>(P0, P1, P2, t_feat, featb);
    fsrc = featb;
  }

  // ---- prediction head ----
  concat_kernel<<<(BS * (H / 4) + 255) / 256, 256, 0, stream>>>(x, t_feat, inpb);

  gemm_nt_mfma<0, 0, 1><<<dim3(1, 48, 1), 256, 0, stream>>>(
      inpb, wq4tb, wq4t_b, t_qk, nullptr, 0,
      64, 2 * H, 2 * H, 2 * H, 64, 1.f, 1, 0, 0, 0, 0, 0, 0);
  rope(t_qk, qb, 1);
  gemm_nt_mfma<0, 0, 1><<<dim3(1, 48, 1), 256, 0, stream>>>(
      inpb, wk4tb, wk4t_b, t_qk, nullptr, 0,
      64, 2 * H, 2 * H, 2 * H, 64, 1.f, 1, 0, 0, 0, 0, 0, 0);
  rope(t_qk, kb, 1);
  gemm_nt_mfma<1, 3, 1><<<dim3(3, 3, B), 256, 0, stream>>>(
      qb, kb, nullptr, nullptr, out, 6,
      S, 64, 64, 64, S, INV, 1,
      (long long)S * 64, 0, (long long)S * 64, 0, 0, 0);

  gemm_nt_mfma<1, 1, 1><<<dim3(8, 48, 1), 256, 0, stream>>>(
      inpb, wq_repb, wq_rep_b, repb, nullptr, 0,
      960, 2 * H, 2 * H, 2 * H, 960, 1.f, 1, 0, 0, 0, 0, 0, 0);
  gemm_nt_mfma<0, 0, 1><<<dim3(3, 48, 1), 256, 0, stream>>>(
      repb, wq_scb, wq_sc_b, t_qk, nullptr, 0,
      384, 960, 960, 960, 384, 1.f, 1, 0, 0, 0, 0, 0, 0);
  rope(t_qk, qb, 6);
  gemm_nt_mfma<1, 1, 1><<<dim3(8, 48, 1), 256, 0, stream>>>(
      inpb, wk_repb, wk_rep_b, repb, nullptr, 0,
      960, 2 * H, 2 * H, 2 * H, 960, 1.f, 1, 0, 0, 0, 0, 0, 0);
  gemm_nt_mfma<0, 0, 1><<<dim3(3, 48, 1), 256, 0, stream>>>(
      repb, wk_scb, wk_sc_b, t_qk, nullptr, 0,
      384, 960, 960, 960, 384, 1.f, 1, 0, 0, 0, 0, 0, 0);
  rope(t_qk, kb, 6);
  gemm_nt_mfma<0, 3, 1><<<dim3(3, 3, B * 6), 256, 0, stream>>>(
      qb, kb, nullptr, nullptr, out, 0,
      S, 64, 384, 384, S, INV, 6,
      (long long)S * 384, 64, (long long)S * 384, 64, 0, 0);
}

// Round 5
// 886.131 us; speedup vs baseline: 6.1239x; 1.1337x over previous
//
#include <hip/hip_runtime.h>
#include <math.h>

typedef unsigned short ushort_t;
typedef __attribute__((ext_vector_type(8))) short short8;
typedef __attribute__((ext_vector_type(4))) float f32x4;

// ---------------- problem constants ----------------
constexpr int B = 16, S = 384, H = 768;
constexpr int BS = B * S;                                // 6144
constexpr long long PAIRS = (long long)S * (S + 1) / 2;  // 73920
constexpr float INV = 0.125f;                            // 1/sqrt(64)

__device__ __forceinline__ ushort_t f2bf(float f) {
  unsigned int u = __float_as_uint(f);
  u += 0x7FFF + ((u >> 16) & 1);       // round-to-nearest-even
  return (ushort_t)(u >> 16);
}
__device__ __forceinline__ float bf2f(ushort_t u) {
  return __uint_as_float(((unsigned int)u) << 16);
}

__device__ __forceinline__ void glds16(const ushort_t* g, ushort_t* l) {
  __builtin_amdgcn_global_load_lds(
      (const __attribute__((address_space(1))) unsigned int*)g,
      (__attribute__((address_space(3))) unsigned int*)l, 16, 0, 0);
}

// ---------------- rope table ----------------
__global__ void rope_table_kernel(float* tab) {
  int s = blockIdx.x, i = threadIdx.x;  // 384 x 32
  double ang = (double)s / pow(10000.0, (double)i / 32.0);
  tab[s * 64 + 2 * i]     = (float)cos(ang);
  tab[s * 64 + 2 * i + 1] = (float)sin(ang);
}

// ---------------- bulk fp32 -> bf16 convert with zero tail padding ----------------
constexpr int NJOBS = 14;
struct CvtJobs {
  const float* src[NJOBS];
  ushort_t* dst[NJOBS];
  int n_real[NJOBS];
  int n_tot[NJOBS];
  int blk_off[NJOBS + 1];
};
__global__ __launch_bounds__(256) void cvt_jobs_kernel(CvtJobs J) {
  int blk = blockIdx.x;
  int j = 0;
  while (j < NJOBS - 1 && blk >= J.blk_off[j + 1]) ++j;
  int i4 = (blk - J.blk_off[j]) * 256 + threadIdx.x;
  if (i4 * 4 >= J.n_tot[j]) return;
  ushort4 o;
  if (i4 * 4 < J.n_real[j]) {
    float4 v = ((const float4*)J.src[j])[i4];
    o = make_ushort4(f2bf(v.x), f2bf(v.y), f2bf(v.z), f2bf(v.w));
  } else {
    o = make_ushort4(0, 0, 0, 0);
  }
  ((ushort4*)J.dst[j])[i4] = o;
}

// ---------------- concat q/k bias pairs into combined fp32 buffers ----------------
__global__ __launch_bounds__(256) void bias_concat_kernel(
    const float* q1, const float* k1, const float* q2, const float* k2,
    const float* q3, const float* k3, const float* q4, const float* k4,
    float* d1, float* d2, float* d3, float* d4) {
  int t = blockIdx.x * blockDim.x + threadIdx.x;
  if (t < 128)  d1[t] = (t < 64)  ? q1[t] : k1[t - 64];
  if (t < 128)  d2[t] = (t < 64)  ? q2[t] : k2[t - 64];
  if (t < 1344) d3[t] = (t < 672) ? q3[t] : k3[t - 672];
  if (t < 1920) d4[t] = (t < 960) ? q4[t] : k4[t - 960];
}

// ---------------- MFMA NT GEMM, 2-phase pipelined ----------------
// A: [M,K] bf16 (lda), W: [Npad,K] bf16 (ldw, rows zero-padded to 128-mult).
// CMODE 0: fp32 C[M,N] ldc.  1: bf16 C[M,N] ldc.
// 2: bf16 transposed per-batch-of-S rows via LDS: C[bb*sCb + n*ldc + s].
// 3: triu-gather only: gout[(zb*PAIRS+p)*16 + cbase + zh] (n>=m).
// 4: bf16 matrix (ldc) AND fp32 triu-gather for zh<8 at cbase+zh.
// 5: rope+mask epilogue -> bf16: pairs via shfl_xor(1); cbase = nsplit,
//    n<nsplit -> Cv[m*ldc+n], else (float*)gout as Ck[m*ldc2+(n-nsplit)].
// Batched over blockIdx.z, (zb,zh)=(z/nh,z%nh). 128x128 tile, 4 waves, BK=32.
// SWZ: XCD chunking + GROUP_M=8 row-banding for L2 locality.
template <int ACT, int CMODE, int SWZ>
__global__ __launch_bounds__(256) void gemm_nt_mfma(
    const ushort_t* __restrict__ A, const ushort_t* __restrict__ W,
    const float* __restrict__ bias, void* __restrict__ Cv,
    float* __restrict__ gout, int cbase,
    int N, int K, int lda, int ldw, int ldc, float alpha, int nh,
    long long sAb, long long sAh, long long sWb, long long sWh,
    long long sCb, long long sCh,
    const float* __restrict__ mask, const float* __restrict__ tab, int ldc2) {
  constexpr int SHSZ = (CMODE == 2) ? 17408 : 16384;
  __shared__ __align__(16) ushort_t SH[SHSZ];
  int bx = blockIdx.x, by = blockIdx.y, bz = blockIdx.z;
  if (SWZ) {  // requires nwg % 8 == 0 (all our grids)
    const int nx = gridDim.x, ny = gridDim.y;
    const int nwg = nx * ny * gridDim.z;
    const int hw = bx + nx * (by + ny * bz);
    int l = (hw & 7) * (nwg >> 3) + (hw >> 3);
    const int pz = l / (nx * ny);
    int l2 = l - pz * (nx * ny);
    const int GM = 8;
    const int band = l2 / (GM * nx);
    const int rem = l2 - band * (GM * nx);
    const int gm = (ny - band * GM < GM) ? (ny - band * GM) : GM;
    bx = rem / gm;
    by = band * GM + (rem - bx * gm);
    bz = pz;
  }
  const int zb = bz / nh, zh = bz - zb * nh;
  A += zb * sAb + zh * sAh;
  W += zb * sWb + zh * sWh;
  const int t = threadIdx.x;
  const int m0 = by * 128, n0 = bx * 128;
  const int lane = t & 63, wid = t >> 6;
  const int wr = wid >> 1, wc = wid & 1;
  const int lrow = lane & 15, lk = lane >> 4;
  const int srow = t >> 2, sch = (t & 3) * 8;
  const ushort_t* Ag = A + (size_t)(m0 + srow) * lda + sch;
  const ushort_t* Wg = W + (size_t)(n0 + srow) * ldw + sch;
  const size_t a64 = (size_t)64 * lda, w64 = (size_t)64 * ldw;

  f32x4 acc[4][4];
#pragma unroll
  for (int i = 0; i < 4; ++i)
#pragma unroll
    for (int j = 0; j < 4; ++j) acc[i][j] = (f32x4){0.f, 0.f, 0.f, 0.f};

  auto stage = [&](int k0, int buf) {
    const int ao = buf * 4096, bo = 8192 + buf * 4096;
    glds16(Ag + k0, &SH[ao + t * 8]);
    glds16(Ag + k0 + a64, &SH[ao + 2048 + t * 8]);
    glds16(Wg + k0, &SH[bo + t * 8]);
    glds16(Wg + k0 + w64, &SH[bo + 2048 + t * 8]);
  };

  const int nk = K >> 5;
  stage(0, 0);
  for (int s = 0; s < nk; ++s) {
    __syncthreads();                       // stage(s) visible; prev reads done
    if (s + 1 < nk) stage((s + 1) << 5, (s + 1) & 1);
    const int ao = (s & 1) * 4096, bo = 8192 + (s & 1) * 4096;
    short8 av[4], bv[4];
#pragma unroll
    for (int i = 0; i < 4; ++i) {
      av[i] = *(const short8*)&SH[ao + (wr * 64 + i * 16 + lrow) * 32 + lk * 8];
      bv[i] = *(const short8*)&SH[bo + (wc * 64 + i * 16 + lrow) * 32 + lk * 8];
    }
#pragma unroll
    for (int i = 0; i < 4; ++i)
#pragma unroll
      for (int j = 0; j < 4; ++j)
        acc[i][j] = __builtin_amdgcn_mfma_f32_16x16x32_bf16(av[i], bv[j],
                                                            acc[i][j], 0, 0, 0);
  }

  if (CMODE == 2) {
    // LDS-staged transposed epilogue: tile [n_local][s_local], stride 136
    __syncthreads();
    const int bb = m0 / S;
    ushort_t* Cb = (ushort_t*)Cv + (size_t)bb * sCb;
    const int s_base = m0 - bb * S;
#pragma unroll
    for (int i = 0; i < 4; ++i) {
      const int sl = wr * 64 + i * 16 + lk * 4;
#pragma unroll
      for (int j = 0; j < 4; ++j) {
        const int nl = wc * 64 + j * 16 + lrow;
        ushort4 o = make_ushort4(f2bf(acc[i][j][0]), f2bf(acc[i][j][1]),
                                 f2bf(acc[i][j][2]), f2bf(acc[i][j][3]));
        *(ushort4*)&SH[nl * 136 + sl] = o;
      }
    }
    __syncthreads();
#pragma unroll
    for (int it = 0; it < 8; ++it) {
      const int row = it * 16 + wid * 4 + lk;
      ushort_t* dst = Cb + (size_t)(n0 + row) * ldc + s_base + lrow * 8;
      *(short8*)dst = *(const short8*)&SH[row * 136 + lrow * 8];
    }
  } else if (CMODE == 3) {
#pragma unroll
    for (int j = 0; j < 4; ++j) {
      const int n = n0 + wc * 64 + j * 16 + lrow;
#pragma unroll
      for (int i = 0; i < 4; ++i) {
#pragma unroll
        for (int e = 0; e < 4; ++e) {
          const int m = m0 + wr * 64 + i * 16 + lk * 4 + e;
          if (n >= m) {
            long long p = (long long)m * S - (long long)m * (m - 1) / 2 + (n - m);
            float v = alpha * acc[i][j][e];
            if (ACT == 1) v = fmaxf(v, 0.f);
            gout[((size_t)zb * PAIRS + p) * 16 + cbase + zh] = v;
          }
        }
      }
    }
  } else if (CMODE == 4) {
    ushort_t* Cu = (ushort_t*)Cv + zb * sCb + zh * sCh;
#pragma unroll
    for (int j = 0; j < 4; ++j) {
      const int n = n0 + wc * 64 + j * 16 + lrow;
#pragma unroll
      for (int i = 0; i < 4; ++i) {
#pragma unroll
        for (int e = 0; e < 4; ++e) {
          const int m = m0 + wr * 64 + i * 16 + lk * 4 + e;
          float v = alpha * acc[i][j][e];
          Cu[(size_t)m * ldc + n] = f2bf(v);
          if (zh < 8 && n >= m) {
            long long p = (long long)m * S - (long long)m * (m - 1) / 2 + (n - m);
            gout[((size_t)zb * PAIRS + p) * 16 + cbase + zh] = v;
          }
        }
      }
    }
  } else if (CMODE == 5) {
    // bias -> rope(pair via shfl_xor 1) -> mask -> bf16 store
    ushort_t* Cq = (ushort_t*)Cv;
    ushort_t* Ck = (ushort_t*)gout;
    const int nsplit = cbase;
#pragma unroll
    for (int j = 0; j < 4; ++j) {
      const int n = n0 + wc * 64 + j * 16 + lrow;
      const float vb = (n < N) ? bias[n] : 0.f;
      const int d = n & 63;
      const int ti = d & ~1;
#pragma unroll
      for (int i = 0; i < 4; ++i) {
#pragma unroll
        for (int e = 0; e < 4; ++e) {
          const int m = m0 + wr * 64 + i * 16 + lk * 4 + e;
          const int s = m % S;
          float v = (n < N) ? (alpha * acc[i][j][e] + vb) : 0.f;
          float pv = __shfl_xor(v, 1);
          float c = tab[s * 64 + ti], sn = tab[s * 64 + ti + 1];
          float o = (d & 1) ? (v * c + pv * sn) : (v * c - pv * sn);
          o *= mask[m];
          if (n < N) {
            if (n < nsplit) Cq[(size_t)m * ldc + n] = f2bf(o);
            else            Ck[(size_t)m * ldc2 + (n - nsplit)] = f2bf(o);
          }
        }
      }
    }
  } else {
    float* Cf = (float*)Cv + zb * sCb + zh * sCh;
    ushort_t* Cu = (ushort_t*)Cv + zb * sCb + zh * sCh;
#pragma unroll
    for (int j = 0; j < 4; ++j) {
      const int n = n0 + wc * 64 + j * 16 + lrow;
      if (n < N) {
        const float vb = bias ? bias[n] : 0.f;
#pragma unroll
        for (int i = 0; i < 4; ++i) {
          const int m = m0 + wr * 64 + i * 16 + lk * 4;
#pragma unroll
          for (int e = 0; e < 4; ++e) {
            float v = alpha * acc[i][j][e] + vb;
            if (ACT == 1) v = fmaxf(v, 0.f);
            if (CMODE == 0) Cf[(size_t)(m + e) * ldc + n] = v;
            else            Cu[(size_t)(m + e) * ldc + n] = f2bf(v);
          }
        }
      }
    }
  }
}

// ---------------- adj bmm: P[rg] = sum_{r in group} relu(adj[b,r] @ hr[b,r]) ----------------
__global__ __launch_bounds__(256) void adj_bmm_kernel(
    const ushort_t* __restrict__ adjb, const ushort_t* __restrict__ hrt,
    float* __restrict__ P0, float* __restrict__ P1, float* __restrict__ P2) {
  __shared__ __align__(16) ushort_t As[2][128 * 32];
  __shared__ __align__(16) ushort_t Bs[2][128 * 32];
  int bx = blockIdx.x, by = blockIdx.y, bz = blockIdx.z;
  {   // XCD swizzle (nwg = 864, %8==0)
    int nx = gridDim.x, ny = gridDim.y;
    int nwg = nx * ny * gridDim.z;
    int flat = bx + nx * (by + ny * bz);
    int l = (flat & 7) * (nwg >> 3) + (flat >> 3);
    bx = l % nx; l /= nx; by = l % ny; bz = l / ny;
  }
  const int b = bz / 3, rg = bz - b * 3;
  float* P = (rg == 0) ? P0 : (rg == 1) ? P1 : P2;
  const int t = threadIdx.x;
  const int m0 = by * 128, n0 = bx * 128;
  const int lane = t & 63, wid = t >> 6;
  const int wr = wid >> 1, wc = wid & 1;
  const int lrow = lane & 15, lk = lane >> 4;
  const int srow = t >> 2, sch = (t & 3) * 8;

  const ushort_t* adjA =
      adjb + ((size_t)(b * 9 + rg * 3) * S + m0 + srow) * S + sch;
  const ushort_t* hrA =
      hrt + ((size_t)(b * 9 + rg * 3) * H + n0 + srow) * S + sch;

  float mac[4][4][4];
#pragma unroll
  for (int i = 0; i < 4; ++i)
#pragma unroll
    for (int j = 0; j < 4; ++j)
#pragma unroll
      for (int e = 0; e < 4; ++e) mac[i][j][e] = 0.f;

  f32x4 acc[4][4];
#pragma unroll
  for (int i = 0; i < 4; ++i)
#pragma unroll
    for (int j = 0; j < 4; ++j) acc[i][j] = (f32x4){0.f, 0.f, 0.f, 0.f};

  auto stage = [&](int s, int buf) {
    const int rr = s / 12;
    const int k0 = (s - rr * 12) * 32;
    const ushort_t* Ag = adjA + (size_t)rr * S * S + k0;
    const ushort_t* Wg = hrA + (size_t)rr * H * S + k0;
    glds16(Ag, &As[buf][t * 8]);
    glds16(Ag + 64 * S, &As[buf][2048 + t * 8]);
    glds16(Wg, &Bs[buf][t * 8]);
    glds16(Wg + 64 * S, &Bs[buf][2048 + t * 8]);
  };

  stage(0, 0);
  for (int s = 0; s < 36; ++s) {
    __syncthreads();
    if (s + 1 < 36) stage(s + 1, (s + 1) & 1);
    const int buf = s & 1;
    short8 av[4], bv[4];
#pragma unroll
    for (int i = 0; i < 4; ++i) {
      av[i] = *(const short8*)&As[buf][(wr * 64 + i * 16 + lrow) * 32 + lk * 8];
      bv[i] = *(const short8*)&Bs[buf][(wc * 64 + i * 16 + lrow) * 32 + lk * 8];
    }
#pragma unroll
    for (int i = 0; i < 4; ++i)
#pragma unroll
      for (int j = 0; j < 4; ++j)
        acc[i][j] = __builtin_amdgcn_mfma_f32_16x16x32_bf16(av[i], bv[j],
                                                            acc[i][j], 0, 0, 0);
    if ((s % 12) == 11) {   // relation boundary: relu-accumulate, reset
#pragma unroll
      for (int i = 0; i < 4; ++i)
#pragma unroll
        for (int j = 0; j < 4; ++j) {
#pragma unroll
          for (int e = 0; e < 4; ++e)
            mac[i][j][e] += fmaxf(acc[i][j][e], 0.f);
          acc[i][j] = (f32x4){0.f, 0.f, 0.f, 0.f};
        }
    }
  }

#pragma unroll
  for (int i = 0; i < 4; ++i)
#pragma unroll
    for (int j = 0; j < 4; ++j)
#pragma unroll
      for (int e = 0; e < 4; ++e) {
        const int m = m0 + wr * 64 + i * 16 + lk * 4 + e;
        const int n = n0 + wc * 64 + j * 16 + lrow;
        P[((size_t)b * S + m) * H + n] = mac[i][j][e];
      }
}

// ---------------- tiled symmetrize (bf16): lower <- upper^T ----------------
__global__ __launch_bounds__(256) void sym_transpose_kernel(ushort_t* __restrict__ Mt) {
  __shared__ ushort_t T[32][33];
  int tp = blockIdx.x;                 // 0..77 upper-tile pairs (12x13/2)
  int ti = 0;
  { int rem = tp, left = 12;
    while (rem >= left) { rem -= left; ++ti; --left; }
    tp = rem; }
  const int tj = ti + tp;
  ushort_t* base = Mt + (size_t)blockIdx.y * S * S;
  const int r = threadIdx.x >> 5, c = threadIdx.x & 31;
#pragma unroll
  for (int k = 0; k < 4; ++k)
    T[r + 8 * k][c] = base[(size_t)(ti * 32 + r + 8 * k) * S + tj * 32 + c];
  __syncthreads();
  if (ti == tj) {
#pragma unroll
    for (int k = 0; k < 4; ++k)
      if ((r + 8 * k) > c)
        base[(size_t)(ti * 32 + r + 8 * k) * S + tj * 32 + c] = T[c][r + 8 * k];
  } else {
#pragma unroll
    for (int k = 0; k < 4; ++k)
      base[(size_t)(tj * 32 + r + 8 * k) * S + ti * 32 + c] = T[c][r + 8 * k];
  }
}

// ---------------- softmax row + (att!=0) mask: bf16 in -> bf16 adj ----------------
__global__ __launch_bounds__(128) void softmax_mask_kernel(
    const ushort_t* __restrict__ Mt, ushort_t* __restrict__ adjb) {
  __shared__ float red[128];
  int row = blockIdx.x;                // B*9*S rows
  const ushort_t* r = Mt + (size_t)row * S;
  ushort_t* o = adjb + (size_t)row * S;
  int t = threadIdx.x;
  float v[3];
  float mx = -INFINITY;
#pragma unroll
  for (int q = 0; q < 3; ++q) { v[q] = bf2f(r[t + q * 128]); mx = fmaxf(mx, v[q]); }
  red[t] = mx; __syncthreads();
  for (int off = 64; off > 0; off >>= 1) {
    if (t < off) red[t] = fmaxf(red[t], red[t + off]);
    __syncthreads();
  }
  mx = red[0]; __syncthreads();
  float e[3], s = 0.f;
#pragma unroll
  for (int q = 0; q < 3; ++q) { e[q] = expf(v[q] - mx); s += e[q]; }
  red[t] = s; __syncthreads();
  for (int off = 64; off > 0; off >>= 1) {
    if (t < off) red[t] += red[t + off];
    __syncthreads();
  }
  float invs = 1.f / red[0];
#pragma unroll
  for (int q = 0; q < 3; ++q)
    o[t + q * 128] = f2bf((v[q] != 0.f) ? e[q] * invs : 0.f);
}

// ---------------- RGAT finalize: feat = LN((P0+P1+P2)/9) ----------------
__global__ __launch_bounds__(256) void ln_finalize_kernel(
    const float* __restrict__ P0, const float* __restrict__ P1,
    const float* __restrict__ P2, float* __restrict__ feat,
    ushort_t* __restrict__ featb) {
  __shared__ float red[256];
  int row = blockIdx.x;
  const size_t base = (size_t)row * H;
  float* f = feat + base;
  ushort_t* fb = featb + base;
  int t = threadIdx.x;
  float v[3];
  float s = 0.f;
#pragma unroll
  for (int q = 0; q < 3; ++q) {
    size_t ix = base + t + q * 256;
    v[q] = (P0[ix] + P1[ix] + P2[ix]) / 9.0f;   // terms >= 0, relu is no-op
    s += v[q];
  }
  red[t] = s; __syncthreads();
  for (int off = 128; off > 0; off >>= 1) {
    if (t < off) red[t] += red[t + off];
    __syncthreads();
  }
  float mean = red[0] / (float)H; __syncthreads();
  float s2 = 0.f;
#pragma unroll
  for (int q = 0; q < 3; ++q) { float d = v[q] - mean; s2 += d * d; }
  red[t] = s2; __syncthreads();
  for (int off = 128; off > 0; off >>= 1) {
    if (t < off) red[t] += red[t + off];
    __syncthreads();
  }
  float var = red[0] / (float)H;
  float rs = rsqrtf(var + 1e-5f);
#pragma unroll
  for (int q = 0; q < 3; ++q) {
    float o = (v[q] - mean) * rs;
    f[t + q * 256] = o;
    fb[t + q * 256] = f2bf(o);
  }
}

// ---------------- concat [x, feat] -> bf16 inp [BS, 1536] ----------------
__global__ __launch_bounds__(256) void concat_kernel(
    const float* __restrict__ x, const float* __restrict__ feat,
    ushort_t* __restrict__ inp) {
  int idx = blockIdx.x * blockDim.x + threadIdx.x;  // BS*192 float4 groups
  if (idx >= BS * (H / 4)) return;
  int bs = idx / (H / 4), c4 = idx - bs * (H / 4);
  float4 vx = ((const float4*)x)[idx];
  float4 vf = ((const float4*)feat)[idx];
  ((ushort4*)inp)[(size_t)bs * (2 * H / 4) + c4] =
      make_ushort4(f2bf(vx.x), f2bf(vx.y), f2bf(vx.z), f2bf(vx.w));
  ((ushort4*)inp)[(size_t)bs * (2 * H / 4) + (H / 4) + c4] =
      make_ushort4(f2bf(vf.x), f2bf(vf.y), f2bf(vf.z), f2bf(vf.w));
}

// ---------------- launch ----------------
extern "C" void kernel_launch(void* const* d_in, const int* in_sizes, int n_in,
                              void* d_out, int out_size, void* d_ws, size_t ws_size,
                              hipStream_t stream) {
  (void)in_sizes; (void)n_in; (void)out_size; (void)ws_size;
  const float* x          = (const float*)d_in[0];
  const float* mask       = (const float*)d_in[1];
  const float* wq4gt_w    = (const float*)d_in[2];
  const float* wq4gt_b    = (const float*)d_in[3];
  const float* wk4gt_w    = (const float*)d_in[4];
  const float* wk4gt_b    = (const float*)d_in[5];
  const float* wq4g_rep_w = (const float*)d_in[6];
  const float* wq4g_rep_b = (const float*)d_in[7];
  const float* wq4g_sc_w  = (const float*)d_in[8];
  const float* wq4g_sc_b  = (const float*)d_in[9];
  const float* wk4g_rep_w = (const float*)d_in[10];
  const float* wk4g_rep_b = (const float*)d_in[11];
  const float* wk4g_sc_w  = (const float*)d_in[12];
  const float* wk4g_sc_b  = (const float*)d_in[13];
  const float* rgat_w     = (const float*)d_in[14];
  const float* wq4t_w     = (const float*)d_in[15];
  const float* wq4t_b     = (const float*)d_in[16];
  const float* wk4t_w     = (const float*)d_in[17];
  const float* wk4t_b     = (const float*)d_in[18];
  const float* wq_rep_w   = (const float*)d_in[19];
  const float* wq_rep_b   = (const float*)d_in[20];
  const float* wq_sc_w    = (const float*)d_in[21];
  const float* wq_sc_b    = (const float*)d_in[22];
  const float* wk_rep_w   = (const float*)d_in[23];
  const float* wk_rep_b   = (const float*)d_in[24];
  const float* wk_sc_w    = (const float*)d_in[25];
  const float* wk_sc_b    = (const float*)d_in[26];
  float* out = (float*)d_out;

  // ---- workspace carve-up (256B aligned) ----
  char* wsb = (char*)d_ws;
  size_t off = 0;
  auto af = [&](size_t n) { float* p = (float*)(wsb + off);
                            off += ((n * 4 + 255) & ~(size_t)255); return p; };
  auto au = [&](size_t n) { ushort_t* p = (ushort_t*)(wsb + off);
                            off += ((n * 2 + 255) & ~(size_t)255); return p; };

  float* t_rope = af(24576);
  float* t_scg  = af((size_t)B * 9 * S * S);      // bf16 score / bf16 hr_t region
  float* t_acc  = af((size_t)BS * H);             // RGAT partial P0
  float* t_feat = af((size_t)BS * H);
  ushort_t* xb    = au((size_t)BS * H);
  ushort_t* featb = au((size_t)BS * H);
  ushort_t* inpb  = au((size_t)BS * 2 * H);       // P2 alias during RGAT
  ushort_t* repb  = au((size_t)BS * 1920);        // P1 alias during RGAT
  ushort_t* qb    = au((size_t)BS * 576);
  ushort_t* kb    = au((size_t)BS * 576);
  ushort_t* adjb  = au((size_t)B * 9 * S * S);
  ushort_t* wqk4gtb   = au(98304);       // [128, 768]
  ushort_t* wqk4tb    = au(196608);      // [128, 1536]
  ushort_t* wqk4g_repb = au(1081344);    // [1408, 768] (1344 real)
  ushort_t* wqk_repb   = au(2949120);    // [1920, 1536]
  ushort_t* wq4g_scb  = au(430080);      // [640, 672] (576 real)
  ushort_t* wk4g_scb  = au(430080);
  ushort_t* wq_scb    = au(368640);      // [384, 960]
  ushort_t* wk_scb    = au(368640);
  ushort_t* rgatb     = au(10616832);
  float* bqk4gt   = af(128);
  float* bqk4t    = af(128);
  float* bqk4g_rep = af(1344);
  float* bqk_rep   = af(1920);

  ushort_t* scg_u = (ushort_t*)t_scg;        // bf16 score matrix [B,9,S,S]
  ushort_t* hr_t  = (ushort_t*)t_scg;        // bf16 [B,9,H,S] (after adj built)
  float* P0 = t_acc;                         // partials, each >= BS*H*4 bytes
  float* P1 = (float*)repb;                  // BS*1920*2 B >= BS*H*4 B
  float* P2 = (float*)inpb;                  // BS*3072 B == BS*H*4 B

  rope_table_kernel<<<S, 32, 0, stream>>>(t_rope);

  // ---- bulk convert weights (+x) to bf16 into combined/padded buffers ----
  {
    CvtJobs J;
    const float* srcs[NJOBS] = {wq4gt_w, wk4gt_w, wq4t_w, wk4t_w,
                                wq4g_rep_w, wk4g_rep_w, wq_rep_w, wk_rep_w,
                                wq4g_sc_w, wk4g_sc_w, wq_sc_w, wk_sc_w,
                                rgat_w, x};
    ushort_t* dsts[NJOBS] = {wqk4gtb, wqk4gtb + 49152, wqk4tb, wqk4tb + 98304,
                             wqk4g_repb, wqk4g_repb + 516096,
                             wqk_repb, wqk_repb + 1474560,
                             wq4g_scb, wk4g_scb, wq_scb, wk_scb,
                             rgatb, xb};
    int nreal[NJOBS] = {49152, 49152, 98304, 98304,
                        516096, 516096, 1474560, 1474560,
                        387072, 387072, 368640, 368640,
                        10616832, 4718592};
    int ntot[NJOBS]  = {49152, 49152, 98304, 98304,
                        516096, 565248, 1474560, 1474560,
                        430080, 430080, 368640, 368640,
                        10616832, 4718592};
    int acc_blk = 0;
    for (int j = 0; j < NJOBS; ++j) {
      J.src[j] = srcs[j]; J.dst[j] = dsts[j];
      J.n_real[j] = nreal[j]; J.n_tot[j] = ntot[j];
      J.blk_off[j] = acc_blk;
      acc_blk += (ntot[j] + 1023) / 1024;
    }
    J.blk_off[NJOBS] = acc_blk;
    cvt_jobs_kernel<<<acc_blk, 256, 0, stream>>>(J);
  }
  bias_concat_kernel<<<8, 256, 0, stream>>>(
      wq4gt_b, wk4gt_b, wq4t_b, wk4t_b, wq4g_rep_b, wk4g_rep_b,
      wq_rep_b, wk_rep_b, bqk4gt, bqk4t, bqk4g_rep, bqk_rep);

  // ---- graph layer: combined q/k token-pair proj (rope fused) ----
  gemm_nt_mfma<0, 5, 1><<<dim3(1, 48, 1), 256, 0, stream>>>(
      xb, wqk4gtb, bqk4gt, qb, (float*)kb, 64,
      128, 768, 768, 768, 64, 1.f, 1, 0, 0, 0, 0, 0, 0,
      mask, t_rope, 64);
  gemm_nt_mfma<1, 3, 1><<<dim3(3, 3, B), 256, 0, stream>>>(
      qb, kb, nullptr, nullptr, out, 15,
      S, 64, 64, 64, S, INV, 1,
      (long long)S * 64, 0, (long long)S * 64, 0, 0, 0,
      nullptr, nullptr, 0);

  // ---- graph layer: combined rep MLP + per-side sc (rope fused) ----
  gemm_nt_mfma<1, 1, 1><<<dim3(11, 48, 1), 256, 0, stream>>>(
      xb, wqk4g_repb, bqk4g_rep, repb, nullptr, 0,
      1344, 768, 768, 768, 1344, 1.f, 1, 0, 0, 0, 0, 0, 0,
      nullptr, nullptr, 0);
  gemm_nt_mfma<0, 5, 1><<<dim3(5, 48, 1), 256, 0, stream>>>(
      repb, wq4g_scb, wq4g_sc_b, qb, (float*)qb, 1 << 30,
      576, 672, 1344, 672, 576, 1.f, 1, 0, 0, 0, 0, 0, 0,
      mask, t_rope, 576);
  gemm_nt_mfma<0, 5, 1><<<dim3(5, 48, 1), 256, 0, stream>>>(
      repb + 672, wk4g_scb, wk4g_sc_b, kb, (float*)kb, 1 << 30,
      576, 672, 1344, 672, 576, 1.f, 1, 0, 0, 0, 0, 0, 0,
      mask, t_rope, 576);
  gemm_nt_mfma<0, 4, 1><<<dim3(3, 3, B * 9), 256, 0, stream>>>(
      qb, kb, nullptr, scg_u, out, 7,
      S, 64, 576, 576, S, INV, 9,
      (long long)S * 576, 64, (long long)S * 576, 64,
      (long long)9 * S * S, (long long)S * S,
      nullptr, nullptr, 0);
  sym_transpose_kernel<<<dim3(78, B * 9), 256, 0, stream>>>(scg_u);
  softmax_mask_kernel<<<B * 9 * S, 128, 0, stream>>>(scg_u, adjb);

  // ---- RGAT x2 ----
  const ushort_t* fsrc = xb;
  for (int l = 0; l < 2; ++l) {
    gemm_nt_mfma<0, 2, 1><<<dim3(54, 48, 1), 256, 0, stream>>>(
        fsrc, rgatb + (size_t)l * 9 * H * H, nullptr, hr_t, nullptr, 0,
        9 * H, H, H, H, S, 1.f, 1, 0, 0, 0, 0, (long long)9 * H * S, 0,
        nullptr, nullptr, 0);
    adj_bmm_kernel<<<dim3(6, 3, B * 3), 256, 0, stream>>>(adjb, hr_t, P0, P1, P2);
    ln_finalize_kernel<<<BS, 256, 0, stream>>>(P0, P1, P2, t_feat, featb);
    fsrc = featb;
  }

  // ---- prediction head ----
  concat_kernel<<<(BS * (H / 4) + 255) / 256, 256, 0, stream>>>(x, t_feat, inpb);

  gemm_nt_mfma<0, 5, 1><<<dim3(1, 48, 1), 256, 0, stream>>>(
      inpb, wqk4tb, bqk4t, qb, (float*)kb, 64,
      128, 1536, 1536, 1536, 64, 1.f, 1, 0, 0, 0, 0, 0, 0,
      mask, t_rope, 64);
  gemm_nt_mfma<1, 3, 1><<<dim3(3, 3, B), 256, 0, stream>>>(
      qb, kb, nullptr, nullptr, out, 6,
      S, 64, 64, 64, S, INV, 1,
      (long long)S * 64, 0, (long long)S * 64, 0, 0, 0,
      nullptr, nullptr, 0);

  gemm_nt_mfma<1, 1, 1><<<dim3(15, 48, 1), 256, 0, stream>>>(
      inpb, wqk_repb, bqk_rep, repb, nullptr, 0,
      1920, 1536, 1536, 1536, 1920, 1.f, 1, 0, 0, 0, 0, 0, 0,
      nullptr, nullptr, 0);
  gemm_nt_mfma<0, 5, 1><<<dim3(3, 48, 1), 256, 0, stream>>>(
      repb, wq_scb, wq_sc_b, qb, (float*)qb, 1 << 30,
      384, 960, 1920, 960, 384, 1.f, 1, 0, 0, 0, 0, 0, 0,
      mask, t_rope, 384);
  gemm_nt_mfma<0, 5, 1><<<dim3(3, 48, 1), 256, 0, stream>>>(
      repb + 960, wk_scb, wk_sc_b, kb, (float*)kb, 1 << 30,
      384, 960, 1920, 960, 384, 1.f, 1, 0, 0, 0, 0, 0, 0,
      mask, t_rope, 384);
  gemm_nt_mfma<0, 3, 1><<<dim3(3, 3, B * 6), 256, 0, stream>>>(
      qb, kb, nullptr, nullptr, out, 0,
      S, 64, 384, 384, S, INV, 6,
      (long long)S * 384, 64, (long long)S * 384, 64, 0, 0,
      nullptr, nullptr, 0);
}

// Round 8
// 654.961 us; speedup vs baseline: 8.2854x; 1.3530x over previous
//
#include <hip/hip_runtime.h>
#include <math.h>

typedef unsigned short ushort_t;
typedef __attribute__((ext_vector_type(8))) short short8;
typedef __attribute__((ext_vector_type(4))) float f32x4;

// ---------------- problem constants ----------------
constexpr int B = 16, S = 384, H = 768;
constexpr int BS = B * S;                                // 6144
constexpr long long PAIRS = (long long)S * (S + 1) / 2;  // 73920
constexpr float INV = 0.125f;                            // 1/sqrt(64)

__device__ __forceinline__ ushort_t f2bf(float f) {
  unsigned int u = __float_as_uint(f);
  u += 0x7FFF + ((u >> 16) & 1);       // round-to-nearest-even
  return (ushort_t)(u >> 16);
}
__device__ __forceinline__ float bf2f(ushort_t u) {
  return __uint_as_float(((unsigned int)u) << 16);
}

__device__ __forceinline__ void glds16(const ushort_t* g, ushort_t* l) {
  __builtin_amdgcn_global_load_lds(
      (const __attribute__((address_space(1))) unsigned int*)g,
      (__attribute__((address_space(3))) unsigned int*)l, 16, 0, 0);
}

// ---------------- rope table ----------------
__global__ void rope_table_kernel(float* tab) {
  int s = blockIdx.x, i = threadIdx.x;  // 384 x 32
  double ang = (double)s / pow(10000.0, (double)i / 32.0);
  tab[s * 64 + 2 * i]     = (float)cos(ang);
  tab[s * 64 + 2 * i + 1] = (float)sin(ang);
}

// ---------------- bulk fp32 -> bf16 convert with zero tail padding ----------------
constexpr int NJOBS = 14;
struct CvtJobs {
  const float* src[NJOBS];
  ushort_t* dst[NJOBS];
  int n_real[NJOBS];
  int n_tot[NJOBS];
  int blk_off[NJOBS + 1];
};
__global__ __launch_bounds__(256) void cvt_jobs_kernel(CvtJobs J) {
  int blk = blockIdx.x;
  int j = 0;
  while (j < NJOBS - 1 && blk >= J.blk_off[j + 1]) ++j;
  int i4 = (blk - J.blk_off[j]) * 256 + threadIdx.x;
  if (i4 * 4 >= J.n_tot[j]) return;
  ushort4 o;
  if (i4 * 4 < J.n_real[j]) {
    float4 v = ((const float4*)J.src[j])[i4];
    o = make_ushort4(f2bf(v.x), f2bf(v.y), f2bf(v.z), f2bf(v.w));
  } else {
    o = make_ushort4(0, 0, 0, 0);
  }
  ((ushort4*)J.dst[j])[i4] = o;
}

// ---------------- combined bias assembly ----------------
__global__ __launch_bounds__(256) void bias_concat_kernel(
    const float* g_repq, const float* g_repk, const float* g_gtq, const float* g_gtk,
    const float* p_repq, const float* p_repk, const float* p_gtq, const float* p_gtk,
    const float* g_scq, const float* g_sck, const float* p_scq, const float* p_sck,
    float* bqkg, float* bqkp, float* bscg, float* bscp) {
  int t = blockIdx.x * blockDim.x + threadIdx.x;   // 0..2047
  if (t < 1472)
    bqkg[t] = t < 672 ? g_repq[t] : t < 1344 ? g_repk[t - 672]
            : t < 1408 ? g_gtq[t - 1344] : g_gtk[t - 1408];
  if (t < 2048)
    bqkp[t] = t < 960 ? p_repq[t] : t < 1920 ? p_repk[t - 960]
            : t < 1984 ? p_gtq[t - 1920] : p_gtk[t - 1984];
  if (t < 1152) bscg[t] = t < 576 ? g_scq[t] : g_sck[t - 576];
  if (t < 768)  bscp[t] = t < 384 ? p_scq[t] : p_sck[t - 384];
}

// ---------------- MFMA NT GEMM, 2-phase pipelined ----------------
// A: [M,K] bf16 (lda), W: [Npad,K] bf16 (rows zero-padded to 128-mult).
// CMODE 2: bf16 transposed per-batch-of-S rows via LDS: C[bb*sCb + n*ldc + s].
// CMODE 3: triu plane only: pl[(cbase+zh)*B*PAIRS + zb*PAIRS + p] bf16 (n>=m).
// CMODE 4: bf16 matrix (ldc) AND plane for zh<8 at cbase+zh.
// CMODE 5: rope+mask -> bf16 qd[+zh*sCh][m*ldc+n]; bias[zh*biasN+n].
// CMODE 6: n<nsplit -> relu bf16 Cv[m*ldc+n]; nsplit<=n<N -> rope+mask ->
//          d=n-nsplit: d<64 -> qd[m*64+d] else kd[m*64+(d&63)].
// Batched over blockIdx.z, (zb,zh)=(z/nh,z%nh). 128x128 tile, 4 waves, BK=32.
// SWZ: XCD chunking + GROUP_M=8 row-banding for L2 locality.
template <int ACT, int CMODE, int SWZ>
__global__ __launch_bounds__(256) void gemm_nt_mfma(
    const ushort_t* __restrict__ A, const ushort_t* __restrict__ W,
    const float* __restrict__ bias, void* __restrict__ Cv,
    ushort_t* __restrict__ pl, ushort_t* __restrict__ qd,
    ushort_t* __restrict__ kd, int cbase, int nsplit,
    int N, int K, int lda, int ldw, int ldc, float alpha, int nh,
    long long sAb, long long sAh, long long sWb, long long sWh,
    long long sCb, long long sCh,
    const float* __restrict__ mask, const float* __restrict__ tab, int biasN) {
  constexpr int SHSZ = (CMODE == 2) ? 17408 : 16384;
  __shared__ __align__(16) ushort_t SH[SHSZ];
  int bx = blockIdx.x, by = blockIdx.y, bz = blockIdx.z;
  if (SWZ) {  // requires nwg % 8 == 0 (all our grids)
    const int nx = gridDim.x, ny = gridDim.y;
    const int nwg = nx * ny * gridDim.z;
    const int hw = bx + nx * (by + ny * bz);
    int l = (hw & 7) * (nwg >> 3) + (hw >> 3);
    const int pz = l / (nx * ny);
    int l2 = l - pz * (nx * ny);
    const int GM = 8;
    const int band = l2 / (GM * nx);
    const int rem = l2 - band * (GM * nx);
    const int gm = (ny - band * GM < GM) ? (ny - band * GM) : GM;
    bx = rem / gm;
    by = band * GM + (rem - bx * gm);
    bz = pz;
  }
  const int zb = bz / nh, zh = bz - zb * nh;
  A += zb * sAb + zh * sAh;
  W += zb * sWb + zh * sWh;
  const int t = threadIdx.x;
  const int m0 = by * 128, n0 = bx * 128;
  const int lane = t & 63, wid = t >> 6;
  const int wr = wid >> 1, wc = wid & 1;
  const int lrow = lane & 15, lk = lane >> 4;
  const int srow = t >> 2, sch = (t & 3) * 8;
  const ushort_t* Ag = A + (size_t)(m0 + srow) * lda + sch;
  const ushort_t* Wg = W + (size_t)(n0 + srow) * ldw + sch;
  const size_t a64 = (size_t)64 * lda, w64 = (size_t)64 * ldw;

  f32x4 acc[4][4];
#pragma unroll
  for (int i = 0; i < 4; ++i)
#pragma unroll
    for (int j = 0; j < 4; ++j) acc[i][j] = (f32x4){0.f, 0.f, 0.f, 0.f};

  auto stage = [&](int k0, int buf) {
    const int ao = buf * 4096, bo = 8192 + buf * 4096;
    glds16(Ag + k0, &SH[ao + t * 8]);
    glds16(Ag + k0 + a64, &SH[ao + 2048 + t * 8]);
    glds16(Wg + k0, &SH[bo + t * 8]);
    glds16(Wg + k0 + w64, &SH[bo + 2048 + t * 8]);
  };

  const int nk = K >> 5;
  stage(0, 0);
  for (int s = 0; s < nk; ++s) {
    __syncthreads();                       // stage(s) visible; prev reads done
    if (s + 1 < nk) stage((s + 1) << 5, (s + 1) & 1);
    const int ao = (s & 1) * 4096, bo = 8192 + (s & 1) * 4096;
    short8 av[4], bv[4];
#pragma unroll
    for (int i = 0; i < 4; ++i) {
      av[i] = *(const short8*)&SH[ao + (wr * 64 + i * 16 + lrow) * 32 + lk * 8];
      bv[i] = *(const short8*)&SH[bo + (wc * 64 + i * 16 + lrow) * 32 + lk * 8];
    }
#pragma unroll
    for (int i = 0; i < 4; ++i)
#pragma unroll
      for (int j = 0; j < 4; ++j)
        acc[i][j] = __builtin_amdgcn_mfma_f32_16x16x32_bf16(av[i], bv[j],
                                                            acc[i][j], 0, 0, 0);
  }

  if (CMODE == 2) {
    // LDS-staged transposed epilogue: tile [n_local][s_local], stride 136
    __syncthreads();
    const int bb = m0 / S;
    ushort_t* Cb = (ushort_t*)Cv + (size_t)bb * sCb;
    const int s_base = m0 - bb * S;
#pragma unroll
    for (int i = 0; i < 4; ++i) {
      const int sl = wr * 64 + i * 16 + lk * 4;
#pragma unroll
      for (int j = 0; j < 4; ++j) {
        const int nl = wc * 64 + j * 16 + lrow;
        ushort4 o = make_ushort4(f2bf(acc[i][j][0]), f2bf(acc[i][j][1]),
                                 f2bf(acc[i][j][2]), f2bf(acc[i][j][3]));
        *(ushort4*)&SH[nl * 136 + sl] = o;
      }
    }
    __syncthreads();
#pragma unroll
    for (int it = 0; it < 8; ++it) {
      const int row = it * 16 + wid * 4 + lk;
      ushort_t* dst = Cb + (size_t)(n0 + row) * ldc + s_base + lrow * 8;
      *(short8*)dst = *(const short8*)&SH[row * 136 + lrow * 8];
    }
  } else if (CMODE == 3) {
    ushort_t* plc = pl + ((size_t)(cbase + zh) * B + zb) * PAIRS;
#pragma unroll
    for (int j = 0; j < 4; ++j) {
      const int n = n0 + wc * 64 + j * 16 + lrow;
#pragma unroll
      for (int i = 0; i < 4; ++i) {
#pragma unroll
        for (int e = 0; e < 4; ++e) {
          const int m = m0 + wr * 64 + i * 16 + lk * 4 + e;
          if (n >= m) {
            long long p = (long long)m * S - (long long)m * (m - 1) / 2 + (n - m);
            float v = alpha * acc[i][j][e];
            if (ACT == 1) v = fmaxf(v, 0.f);
            plc[p] = f2bf(v);
          }
        }
      }
    }
  } else if (CMODE == 4) {
    ushort_t* Cu = (ushort_t*)Cv + zb * sCb + zh * sCh;
    ushort_t* plc = pl + ((size_t)(cbase + zh) * B + zb) * PAIRS;
#pragma unroll
    for (int j = 0; j < 4; ++j) {
      const int n = n0 + wc * 64 + j * 16 + lrow;
#pragma unroll
      for (int i = 0; i < 4; ++i) {
#pragma unroll
        for (int e = 0; e < 4; ++e) {
          const int m = m0 + wr * 64 + i * 16 + lk * 4 + e;
          float v = alpha * acc[i][j][e];
          ushort_t vb = f2bf(v);
          Cu[(size_t)m * ldc + n] = vb;
          if (zh < 8 && n >= m) {
            long long p = (long long)m * S - (long long)m * (m - 1) / 2 + (n - m);
            plc[p] = vb;
          }
        }
      }
    }
  } else if (CMODE == 5) {
    // bias -> rope(pair via shfl_xor 1) -> mask -> bf16 to qd (+zh*sCh)
    ushort_t* Cq = qd + (size_t)zh * sCh;
    const float* bz = bias + (size_t)zh * biasN;
#pragma unroll
    for (int j = 0; j < 4; ++j) {
      const int n = n0 + wc * 64 + j * 16 + lrow;
      const float vb = (n < N) ? bz[n] : 0.f;
      const int d = n & 63;
      const int ti = d & ~1;
#pragma unroll
      for (int i = 0; i < 4; ++i) {
#pragma unroll
        for (int e = 0; e < 4; ++e) {
          const int m = m0 + wr * 64 + i * 16 + lk * 4 + e;
          const int s = m % S;
          float v = (n < N) ? (acc[i][j][e] + vb) : 0.f;
          float pv = __shfl_xor(v, 1);
          float c = tab[s * 64 + ti], sn = tab[s * 64 + ti + 1];
          float o = (d & 1) ? (v * c + pv * sn) : (v * c - pv * sn);
          o *= mask[m];
          if (n < N) Cq[(size_t)m * ldc + n] = f2bf(o);
        }
      }
    }
  } else if (CMODE == 6) {
    // split epilogue: rep (relu bf16) for n<nsplit, gt rope for nsplit<=n<N
    ushort_t* Cu = (ushort_t*)Cv;
#pragma unroll
    for (int j = 0; j < 4; ++j) {
      const int n = n0 + wc * 64 + j * 16 + lrow;
      const float vb = (n < N) ? bias[n] : 0.f;
#pragma unroll
      for (int i = 0; i < 4; ++i) {
#pragma unroll
        for (int e = 0; e < 4; ++e) {
          const int m = m0 + wr * 64 + i * 16 + lk * 4 + e;
          float v = (n < N) ? (acc[i][j][e] + vb) : 0.f;
          float pv = __shfl_xor(v, 1);
          if (n < nsplit) {
            Cu[(size_t)m * ldc + n] = f2bf(fmaxf(v, 0.f));
          } else if (n < N) {
            const int d = n - nsplit;
            const int dd = d & 63;
            const int ti = dd & ~1;
            const int s = m % S;
            float c = tab[s * 64 + ti], sn = tab[s * 64 + ti + 1];
            float o = (dd & 1) ? (v * c + pv * sn) : (v * c - pv * sn);
            o *= mask[m];
            if (d < 64) qd[(size_t)m * 64 + dd] = f2bf(o);
            else        kd[(size_t)m * 64 + dd] = f2bf(o);
          }
        }
      }
    }
  }
}

// ---------------- adj bmm: P[rg] = sum_{r in group} relu(adj[b,r] @ hr[b,r]) ----------------
__global__ __launch_bounds__(256) void adj_bmm_kernel(
    const ushort_t* __restrict__ adjb, const ushort_t* __restrict__ hrt,
    float* __restrict__ P0, float* __restrict__ P1, float* __restrict__ P2) {
  __shared__ __align__(16) ushort_t As[2][128 * 32];
  __shared__ __align__(16) ushort_t Bs[2][128 * 32];
  int bx = blockIdx.x, by = blockIdx.y, bz = blockIdx.z;
  {   // XCD swizzle (nwg = 864, %8==0)
    int nx = gridDim.x, ny = gridDim.y;
    int nwg = nx * ny * gridDim.z;
    int flat = bx + nx * (by + ny * bz);
    int l = (flat & 7) * (nwg >> 3) + (flat >> 3);
    bx = l % nx; l /= nx; by = l % ny; bz = l / ny;
  }
  const int b = bz / 3, rg = bz - b * 3;
  float* P = (rg == 0) ? P0 : (rg == 1) ? P1 : P2;
  const int t = threadIdx.x;
  const int m0 = by * 128, n0 = bx * 128;
  const int lane = t & 63, wid = t >> 6;
  const int wr = wid >> 1, wc = wid & 1;
  const int lrow = lane & 15, lk = lane >> 4;
  const int srow = t >> 2, sch = (t & 3) * 8;

  const ushort_t* adjA =
      adjb + ((size_t)(b * 9 + rg * 3) * S + m0 + srow) * S + sch;
  const ushort_t* hrA =
      hrt + ((size_t)(b * 9 + rg * 3) * H + n0 + srow) * S + sch;

  float mac[4][4][4];
#pragma unroll
  for (int i = 0; i < 4; ++i)
#pragma unroll
    for (int j = 0; j < 4; ++j)
#pragma unroll
      for (int e = 0; e < 4; ++e) mac[i][j][e] = 0.f;

  f32x4 acc[4][4];
#pragma unroll
  for (int i = 0; i < 4; ++i)
#pragma unroll
    for (int j = 0; j < 4; ++j) acc[i][j] = (f32x4){0.f, 0.f, 0.f, 0.f};

  auto stage = [&](int s, int buf) {
    const int rr = s / 12;
    const int k0 = (s - rr * 12) * 32;
    const ushort_t* Ag = adjA + (size_t)rr * S * S + k0;
    const ushort_t* Wg = hrA + (size_t)rr * H * S + k0;
    glds16(Ag, &As[buf][t * 8]);
    glds16(Ag + 64 * S, &As[buf][2048 + t * 8]);
    glds16(Wg, &Bs[buf][t * 8]);
    glds16(Wg + 64 * S, &Bs[buf][2048 + t * 8]);
  };

  stage(0, 0);
  for (int s = 0; s < 36; ++s) {
    __syncthreads();
    if (s + 1 < 36) stage(s + 1, (s + 1) & 1);
    const int buf = s & 1;
    short8 av[4], bv[4];
#pragma unroll
    for (int i = 0; i < 4; ++i) {
      av[i] = *(const short8*)&As[buf][(wr * 64 + i * 16 + lrow) * 32 + lk * 8];
      bv[i] = *(const short8*)&Bs[buf][(wc * 64 + i * 16 + lrow) * 32 + lk * 8];
    }
#pragma unroll
    for (int i = 0; i < 4; ++i)
#pragma unroll
      for (int j = 0; j < 4; ++j)
        acc[i][j] = __builtin_amdgcn_mfma_f32_16x16x32_bf16(av[i], bv[j],
                                                            acc[i][j], 0, 0, 0);
    if ((s % 12) == 11) {   // relation boundary: relu-accumulate, reset
#pragma unroll
      for (int i = 0; i < 4; ++i)
#pragma unroll
        for (int j = 0; j < 4; ++j) {
#pragma unroll
          for (int e = 0; e < 4; ++e)
            mac[i][j][e] += fmaxf(acc[i][j][e], 0.f);
          acc[i][j] = (f32x4){0.f, 0.f, 0.f, 0.f};
        }
    }
  }

#pragma unroll
  for (int i = 0; i < 4; ++i)
#pragma unroll
    for (int j = 0; j < 4; ++j)
#pragma unroll
      for (int e = 0; e < 4; ++e) {
        const int m = m0 + wr * 64 + i * 16 + lk * 4 + e;
        const int n = n0 + wc * 64 + j * 16 + lrow;
        P[((size_t)b * S + m) * H + n] = mac[i][j][e];
      }
}

// ---------------- tiled symmetrize (bf16): lower <- upper^T ----------------
__global__ __launch_bounds__(256) void sym_transpose_kernel(ushort_t* __restrict__ Mt) {
  __shared__ ushort_t T[32][33];
  int tp = blockIdx.x;                 // 0..77 upper-tile pairs (12x13/2)
  int ti = 0;
  { int rem = tp, left = 12;
    while (rem >= left) { rem -= left; ++ti; --left; }
    tp = rem; }
  const int tj = ti + tp;
  ushort_t* base = Mt + (size_t)blockIdx.y * S * S;
  const int r = threadIdx.x >> 5, c = threadIdx.x & 31;
#pragma unroll
  for (int k = 0; k < 4; ++k)
    T[r + 8 * k][c] = base[(size_t)(ti * 32 + r + 8 * k) * S + tj * 32 + c];
  __syncthreads();
  if (ti == tj) {
#pragma unroll
    for (int k = 0; k < 4; ++k)
      if ((r + 8 * k) > c)
        base[(size_t)(ti * 32 + r + 8 * k) * S + tj * 32 + c] = T[c][r + 8 * k];
  } else {
#pragma unroll
    for (int k = 0; k < 4; ++k)
      base[(size_t)(tj * 32 + r + 8 * k) * S + ti * 32 + c] = T[c][r + 8 * k];
  }
}

// ---------------- softmax row + (att!=0) mask: bf16 in -> bf16 adj ----------------
__global__ __launch_bounds__(128) void softmax_mask_kernel(
    const ushort_t* __restrict__ Mt, ushort_t* __restrict__ adjb) {
  __shared__ float red[128];
  int row = blockIdx.x;                // B*9*S rows
  const ushort_t* r = Mt + (size_t)row * S;
  ushort_t* o = adjb + (size_t)row * S;
  int t = threadIdx.x;
  float v[3];
  float mx = -INFINITY;
#pragma unroll
  for (int q = 0; q < 3; ++q) { v[q] = bf2f(r[t + q * 128]); mx = fmaxf(mx, v[q]); }
  red[t] = mx; __syncthreads();
  for (int off = 64; off > 0; off >>= 1) {
    if (t < off) red[t] = fmaxf(red[t], red[t + off]);
    __syncthreads();
  }
  mx = red[0]; __syncthreads();
  float e[3], s = 0.f;
#pragma unroll
  for (int q = 0; q < 3; ++q) { e[q] = expf(v[q] - mx); s += e[q]; }
  red[t] = s; __syncthreads();
  for (int off = 64; off > 0; off >>= 1) {
    if (t < off) red[t] += red[t + off];
    __syncthreads();
  }
  float invs = 1.f / red[0];
#pragma unroll
  for (int q = 0; q < 3; ++q)
    o[t + q * 128] = f2bf((v[q] != 0.f) ? e[q] * invs : 0.f);
}

// ---------------- RGAT finalize: feat = LN((P0+P1+P2)/9) -> bf16 into inp[:,768:1536] ----------------
// NOTE in-place vs P2(=inp region): all of this block's P2 reads complete
// (syncthreads-separated) before its writes; rows are block-exclusive.
__global__ __launch_bounds__(256) void ln_finalize_kernel(
    const float* __restrict__ P0, const float* __restrict__ P1,
    const float* __restrict__ P2, ushort_t* __restrict__ inp) {
  __shared__ float red[256];
  int row = blockIdx.x;
  const size_t base = (size_t)row * H;
  ushort_t* fb = inp + (size_t)row * (2 * H) + H;
  int t = threadIdx.x;
  float v[3];
  float s = 0.f;
#pragma unroll
  for (int q = 0; q < 3; ++q) {
    size_t ix = base + t + q * 256;
    v[q] = (P0[ix] + P1[ix] + P2[ix]) / 9.0f;   // terms >= 0, relu is no-op
    s += v[q];
  }
  red[t] = s; __syncthreads();
  for (int off = 128; off > 0; off >>= 1) {
    if (t < off) red[t] += red[t + off];
    __syncthreads();
  }
  float mean = red[0] / (float)H; __syncthreads();
  float s2 = 0.f;
#pragma unroll
  for (int q = 0; q < 3; ++q) { float d = v[q] - mean; s2 += d * d; }
  red[t] = s2; __syncthreads();
  for (int off = 128; off > 0; off >>= 1) {
    if (t < off) red[t] += red[t + off];
    __syncthreads();
  }
  float var = red[0] / (float)H;
  float rs = rsqrtf(var + 1e-5f);
#pragma unroll
  for (int q = 0; q < 3; ++q)
    fb[t + q * 256] = f2bf((v[q] - mean) * rs);
}

// ---------------- copy xb -> inp[:,0:768] (short8) ----------------
__global__ __launch_bounds__(256) void copyx_kernel(
    const ushort_t* __restrict__ xb, ushort_t* __restrict__ inp) {
  int idx = blockIdx.x * 256 + threadIdx.x;     // over BS*(H/8) short8 groups
  if (idx >= BS * (H / 8)) return;
  int bs = idx / (H / 8), c8 = idx - bs * (H / 8);
  ((short8*)inp)[(size_t)bs * (2 * H / 8) + c8] = ((const short8*)xb)[idx];
}

// ---------------- final gather: 16 bf16 planes -> out[b,p,16] fp32 ----------------
__global__ __launch_bounds__(256) void gather16_kernel(
    const ushort_t* __restrict__ plA, const ushort_t* __restrict__ plB,
    float* __restrict__ out) {
  int idx = blockIdx.x * 256 + threadIdx.x;          // b*PAIRS + p
  if (idx >= (int)(B * PAIRS)) return;
  const size_t PLN = (size_t)B * PAIRS;
  float v[16];
#pragma unroll
  for (int ch = 0; ch < 7; ++ch)  v[ch] = bf2f(plA[(size_t)ch * PLN + idx]);
#pragma unroll
  for (int ch = 7; ch < 16; ++ch) v[ch] = bf2f(plB[(size_t)(ch - 7) * PLN + idx]);
  float4* dst = (float4*)(out + (size_t)idx * 16);
#pragma unroll
  for (int q = 0; q < 4; ++q)
    dst[q] = make_float4(v[4 * q], v[4 * q + 1], v[4 * q + 2], v[4 * q + 3]);
}

// ---------------- launch ----------------
extern "C" void kernel_launch(void* const* d_in, const int* in_sizes, int n_in,
                              void* d_out, int out_size, void* d_ws, size_t ws_size,
                              hipStream_t stream) {
  (void)in_sizes; (void)n_in; (void)out_size; (void)ws_size;
  const float* x          = (const float*)d_in[0];
  const float* mask       = (const float*)d_in[1];
  const float* wq4gt_w    = (const float*)d_in[2];
  const float* wq4gt_b    = (const float*)d_in[3];
  const float* wk4gt_w    = (const float*)d_in[4];
  const float* wk4gt_b    = (const float*)d_in[5];
  const float* wq4g_rep_w = (const float*)d_in[6];
  const float* wq4g_rep_b = (const float*)d_in[7];
  const float* wq4g_sc_w  = (const float*)d_in[8];
  const float* wq4g_sc_b  = (const float*)d_in[9];
  const float* wk4g_rep_w = (const float*)d_in[10];
  const float* wk4g_rep_b = (const float*)d_in[11];
  const float* wk4g_sc_w  = (const float*)d_in[12];
  const float* wk4g_sc_b  = (const float*)d_in[13];
  const float* rgat_w     = (const float*)d_in[14];
  const float* wq4t_w     = (const float*)d_in[15];
  const float* wq4t_b     = (const float*)d_in[16];
  const float* wk4t_w     = (const float*)d_in[17];
  const float* wk4t_b     = (const float*)d_in[18];
  const float* wq_rep_w   = (const float*)d_in[19];
  const float* wq_rep_b   = (const float*)d_in[20];
  const float* wq_sc_w    = (const float*)d_in[21];
  const float* wq_sc_b    = (const float*)d_in[22];
  const float* wk_rep_w   = (const float*)d_in[23];
  const float* wk_rep_b   = (const float*)d_in[24];
  const float* wk_sc_w    = (const float*)d_in[25];
  const float* wk_sc_b    = (const float*)d_in[26];
  float* out = (float*)d_out;

  // ---- workspace carve-up (256B aligned); total ~267 MB (< R5's proven 274) ----
  char* wsb = (char*)d_ws;
  size_t off = 0;
  auto af = [&](size_t n) { float* p = (float*)(wsb + off);
                            off += ((n * 4 + 255) & ~(size_t)255); return p; };
  auto au = [&](size_t n) { ushort_t* p = (ushort_t*)(wsb + off);
                            off += ((n * 2 + 255) & ~(size_t)255); return p; };

  float* t_rope = af(24576);
  float* t_scg  = af((size_t)B * 9 * S * S);      // bf16 score (half) / bf16 hr_t (full)
  float* t_acc  = af((size_t)BS * H);             // RGAT partial P0
  ushort_t* xb    = au((size_t)BS * H);
  ushort_t* inpb  = au((size_t)BS * 2 * H);       // P2 alias; later [xb|feat] bf16
  ushort_t* repb  = au((size_t)BS * 1920);        // P1 alias; rep outputs
  ushort_t* qb    = au((size_t)BS * 576);         // kb must follow adjacently
  ushort_t* kb    = au((size_t)BS * 576);
  ushort_t* adjb  = au((size_t)B * 9 * S * S);
  ushort_t* plB   = au((size_t)9 * B * PAIRS);    // planes ch 7..15
  ushort_t* wqkg  = au(1179648);     // [1536,768]: repq|repk|gtq|gtk|pad
  ushort_t* wqkp  = au(3145728);     // [2048,1536]: repq|repk|gtq|gtk
  ushort_t* wq4g_scb = au(430080);   // [640,672] (576 real) -- adjacent pair
  ushort_t* wk4g_scb = au(430080);
  ushort_t* wq_scb   = au(368640);   // [384,960] -- adjacent pair
  ushort_t* wk_scb   = au(368640);
  ushort_t* rgatb    = au(10616832); // dead after last hr GEMM -> plA alias
  float* bqkg = af(1472);
  float* bqkp = af(2048);
  float* bscg = af(1152);
  float* bscp = af(768);

  ushort_t* scg_u = (ushort_t*)t_scg;        // bf16 score matrix [B,9,S,S]
  ushort_t* hr_t  = (ushort_t*)t_scg;        // bf16 [B,9,H,S] (after adj built)
  ushort_t* plA   = rgatb;                   // planes ch 0..6 (16.6MB <= 21.2MB)
  float* P0 = t_acc;                         // partials, each >= BS*H*4 bytes
  float* P1 = (float*)repb;                  // 23.6MB region
  float* P2 = (float*)inpb;                  // 18.87MB == BS*H*4 exactly

  rope_table_kernel<<<S, 32, 0, stream>>>(t_rope);

  // ---- bulk convert weights (+x) to bf16 into combined/padded buffers ----
  {
    CvtJobs J;
    const float* srcs[NJOBS] = {wq4g_rep_w, wk4g_rep_w, wq4gt_w, wk4gt_w,
                                wq_rep_w, wk_rep_w, wq4t_w, wk4t_w,
                                wq4g_sc_w, wk4g_sc_w, wq_sc_w, wk_sc_w,
                                rgat_w, x};
    ushort_t* dsts[NJOBS] = {wqkg, wqkg + 516096, wqkg + 1032192, wqkg + 1081344,
                             wqkp, wqkp + 1474560, wqkp + 2949120, wqkp + 3047424,
                             wq4g_scb, wk4g_scb, wq_scb, wk_scb,
                             rgatb, xb};
    int nreal[NJOBS] = {516096, 516096, 49152, 49152,
                        1474560, 1474560, 98304, 98304,
                        387072, 387072, 368640, 368640,
                        10616832, 4718592};
    int ntot[NJOBS]  = {516096, 516096, 49152, 98304,
                        1474560, 1474560, 98304, 98304,
                        430080, 430080, 368640, 368640,
                        10616832, 4718592};
    int acc_blk = 0;
    for (int j = 0; j < NJOBS; ++j) {
      J.src[j] = srcs[j]; J.dst[j] = dsts[j];
      J.n_real[j] = nreal[j]; J.n_tot[j] = ntot[j];
      J.blk_off[j] = acc_blk;
      acc_blk += (ntot[j] + 1023) / 1024;
    }
    J.blk_off[NJOBS] = acc_blk;
    cvt_jobs_kernel<<<acc_blk, 256, 0, stream>>>(J);
  }
  bias_concat_kernel<<<8, 256, 0, stream>>>(
      wq4g_rep_b, wk4g_rep_b, wq4gt_b, wk4gt_b,
      wq_rep_b, wk_rep_b, wq4t_b, wk4t_b,
      wq4g_sc_b, wk4g_sc_b, wq_sc_b, wk_sc_b,
      bqkg, bqkp, bscg, bscp);

  // ---- graph layer: merged rep-MLP + gt-proj (rope fused, split epilogue) ----
  gemm_nt_mfma<0, 6, 1><<<dim3(12, 48, 1), 256, 0, stream>>>(
      xb, wqkg, bqkg, repb, nullptr, qb, kb, 0, 1344,
      1472, 768, 768, 768, 1344, 1.f, 1, 0, 0, 0, 0, 0, 0,
      mask, t_rope, 0);
  gemm_nt_mfma<1, 3, 1><<<dim3(3, 3, B), 256, 0, stream>>>(
      qb, kb, nullptr, nullptr, plB, nullptr, nullptr, 8, 0,   // plane 8 = ch 15
      S, 64, 64, 64, 0, INV, 1,
      (long long)S * 64, 0, (long long)S * 64, 0, 0, 0,
      nullptr, nullptr, 0);

  // ---- graph layer: batched q/k sc projections (rope fused) ----
  gemm_nt_mfma<0, 5, 1><<<dim3(5, 48, 2), 256, 0, stream>>>(
      repb, wq4g_scb, bscg, nullptr, nullptr, qb, nullptr, 0, 0,
      576, 672, 1344, 672, 576, 1.f, 2,
      0, 672, 0, 430080, 0, (long long)BS * 576,
      mask, t_rope, 576);
  gemm_nt_mfma<0, 4, 1><<<dim3(3, 3, B * 9), 256, 0, stream>>>(
      qb, kb, nullptr, scg_u, plB, nullptr, nullptr, 0, 0,     // planes 0..7 = ch 7..14
      S, 64, 576, 576, S, INV, 9,
      (long long)S * 576, 64, (long long)S * 576, 64,
      (long long)9 * S * S, (long long)S * S,
      nullptr, nullptr, 0);
  sym_transpose_kernel<<<dim3(78, B * 9), 256, 0, stream>>>(scg_u);
  softmax_mask_kernel<<<B * 9 * S, 128, 0, stream>>>(scg_u, adjb);

  // ---- RGAT x2 (feat lives in inpb[:,768:1536]) ----
  for (int l = 0; l < 2; ++l) {
    const ushort_t* fsrc = (l == 0) ? xb : inpb + H;
    const int flda = (l == 0) ? H : 2 * H;
    gemm_nt_mfma<0, 2, 1><<<dim3(54, 48, 1), 256, 0, stream>>>(
        fsrc, rgatb + (size_t)l * 9 * H * H, nullptr, hr_t, nullptr, nullptr,
        nullptr, 0, 0,
        9 * H, H, flda, H, S, 1.f, 1, 0, 0, 0, 0, (long long)9 * H * S, 0,
        nullptr, nullptr, 0);
    adj_bmm_kernel<<<dim3(6, 3, B * 3), 256, 0, stream>>>(adjb, hr_t, P0, P1, P2);
    ln_finalize_kernel<<<BS, 256, 0, stream>>>(P0, P1, P2, inpb);
  }
  copyx_kernel<<<(BS * (H / 8) + 255) / 256, 256, 0, stream>>>(xb, inpb);

  // ---- prediction head ----
  gemm_nt_mfma<0, 6, 1><<<dim3(16, 48, 1), 256, 0, stream>>>(
      inpb, wqkp, bqkp, repb, nullptr, qb, kb, 0, 1920,
      2048, 1536, 1536, 1536, 1920, 1.f, 1, 0, 0, 0, 0, 0, 0,
      mask, t_rope, 0);
  gemm_nt_mfma<1, 3, 1><<<dim3(3, 3, B), 256, 0, stream>>>(
      qb, kb, nullptr, nullptr, plA, nullptr, nullptr, 6, 0,   // plane 6 = ch 6
      S, 64, 64, 64, 0, INV, 1,
      (long long)S * 64, 0, (long long)S * 64, 0, 0, 0,
      nullptr, nullptr, 0);

  gemm_nt_mfma<0, 5, 1><<<dim3(3, 48, 2), 256, 0, stream>>>(
      repb, wq_scb, bscp, nullptr, nullptr, qb, nullptr, 0, 0,
      384, 960, 1920, 960, 384, 1.f, 2,
      0, 960, 0, 368640, 0, (long long)BS * 384,
      mask, t_rope, 384);
  gemm_nt_mfma<0, 3, 1><<<dim3(3, 3, B * 6), 256, 0, stream>>>(
      qb, qb + (size_t)BS * 384, nullptr, nullptr, plA, nullptr, nullptr, 0, 0,
      S, 64, 384, 384, 0, INV, 6,
      (long long)S * 384, 64, (long long)S * 384, 64, 0, 0,
      nullptr, nullptr, 0);

  gather16_kernel<<<(int)((B * PAIRS + 255) / 256), 256, 0, stream>>>(plA, plB, out);
}